// Round 17
// baseline (328.801 us; speedup 1.0000x reference)
//
#include <hip/hip_runtime.h>
#include <hip/hip_bf16.h>
#include <math.h>

#define BGR 16
#define NPG 2048
#define HD  128
#define KNN 8
#define NTOT (BGR*NPG)   // 32768

using bf16x8 = __attribute__((ext_vector_type(8))) short;
using f32x4  = __attribute__((ext_vector_type(4))) float;
using f32x16 = __attribute__((ext_vector_type(16))) float;

typedef __attribute__((address_space(3))) unsigned int lds_uint;
typedef const __attribute__((address_space(1))) unsigned int glob_uint;
#define GLOAD_LDS16(g, l) __builtin_amdgcn_global_load_lds((glob_uint*)(g), (lds_uint*)(l), 16, 0, 0)

__device__ inline unsigned short bf16rn(float f) {
    unsigned u = __float_as_uint(f);
    unsigned r = (u + 0x7FFFu + ((u >> 16) & 1u)) >> 16;
    return (unsigned short)r;
}
__device__ inline float bf16tof(unsigned short h) {
    return __uint_as_float(((unsigned)h) << 16);
}

// ---------------- fused setup: encoder+split+sqnorm AND all weight prep ----------------
__device__ inline void wcat_body(const float* __restrict__ Wa,
                                 unsigned short* __restrict__ Wt, int lb, int t)
{
    int gid = lb * 256 + t;        // 32768 = 128k x 256n
    int k = gid >> 8, n = gid & 255;
    float w;
    if (n < 128) w = Wa[(128 + k) * 128 + n];
    else { int nn = n - 128; w = Wa[k * 128 + nn] - Wa[(128 + k) * 128 + nn]; }
    unsigned short b1 = bf16rn(w);  float r1 = w - bf16tof(b1);
    unsigned short b2 = bf16rn(r1);
    int cs = n >> 5, h = (n >> 4) & 1, c = n & 15, kc = k >> 5, kg = (k >> 3) & 3, e = k & 7;
    size_t off = (size_t)cs * 12288 + kc * 1024 + h * 512 + kg * 128 + c * 8 + e;
    Wt[off] = b1; Wt[off + 4096] = b2;
}

__device__ inline void wb_body(const float* __restrict__ Wb,
                               unsigned short* __restrict__ Wt, int lb, int t)
{
    int gid = lb * 256 + t;        // 16384 = 128k x 128n
    int k = gid >> 7, n = gid & 127;
    float w = Wb[k * 128 + n];
    unsigned short b1 = bf16rn(w);  float r1 = w - bf16tof(b1);
    unsigned short b2 = bf16rn(r1);
    int cs = n >> 5, h = (n >> 4) & 1, c = n & 15, kc = k >> 5, kg = (k >> 3) & 3, e = k & 7;
    size_t off = (size_t)cs * 12288 + kc * 1024 + h * 512 + kg * 128 + c * 8 + e;
    Wt[off] = b1; Wt[off + 4096] = b2;
}

__global__ __launch_bounds__(256) void setup_all(const float* __restrict__ x,
                                                 const float* __restrict__ We,
                                                 const float* __restrict__ be,
                                                 unsigned short* __restrict__ hs,
                                                 float* __restrict__ sqg,
                                                 const float* __restrict__ W1a,
                                                 const float* __restrict__ W2a,
                                                 const float* __restrict__ W5a,
                                                 const float* __restrict__ W1b,
                                                 const float* __restrict__ W2b,
                                                 unsigned short* __restrict__ Wt1,
                                                 unsigned short* __restrict__ Wt2,
                                                 unsigned short* __restrict__ Wt5,
                                                 unsigned short* __restrict__ Wbt1,
                                                 unsigned short* __restrict__ Wbt2)
{
    const int bb = blockIdx.x, t = threadIdx.x;
    if (bb < 8192) {
        const size_t plane = (size_t)NTOT * HD;
        int node = (bb * 256 + t) >> 6;
        int lane = t & 63;
        float4 xv = *(const float4*)(x + (size_t)node * 4);
        float v0 = be[lane], v1 = be[lane + 64];
        const float* xf = (const float*)&xv;
#pragma unroll
        for (int f = 0; f < 4; ++f) {
            v0 = fmaf(xf[f], We[f * 128 + lane], v0);
            v1 = fmaf(xf[f], We[f * 128 + lane + 64], v1);
        }
        float s = fmaf(v0, v0, v1 * v1);
#pragma unroll
        for (int off = 32; off >= 1; off >>= 1)
            s += __shfl_xor(s, off);
        if (lane == 0) sqg[node] = s;
#pragma unroll
        for (int q = 0; q < 2; ++q) {
            float v = q ? v1 : v0;
            int   d = lane + q * 64;
            unsigned short b1 = bf16rn(v);  float r1 = v - bf16tof(b1);
            unsigned short b2 = bf16rn(r1);
            size_t base = (size_t)node * HD + d;
            hs[base]         = b1;
            hs[base + plane] = b2;
        }
    }
    else if (bb < 8320) wcat_body(W1a, Wt1, bb - 8192, t);
    else if (bb < 8448) wcat_body(W2a, Wt2, bb - 8320, t);
    else if (bb < 8576) wcat_body(W5a, Wt5, bb - 8448, t);
    else if (bb < 8640) wb_body(W1b, Wbt1, bb - 8576, t);
    else                wb_body(W2b, Wbt2, bb - 8640, t);
}

// 3-pass: A0B0 + A1B0 + A0B1 (drop O(2^-16) A1B1 cross term)
#define THREEPASS(B00,B01,B10,B11) \
    acc0 = __builtin_amdgcn_mfma_f32_16x16x32_bf16(A0[kc], B00, acc0, 0, 0, 0); \
    acc1 = __builtin_amdgcn_mfma_f32_16x16x32_bf16(A0[kc], B01, acc1, 0, 0, 0); \
    acc0 = __builtin_amdgcn_mfma_f32_16x16x32_bf16(A1[kc], B00, acc0, 0, 0, 0); \
    acc1 = __builtin_amdgcn_mfma_f32_16x16x32_bf16(A1[kc], B01, acc1, 0, 0, 0); \
    acc0 = __builtin_amdgcn_mfma_f32_16x16x32_bf16(A0[kc], B10, acc0, 0, 0, 0); \
    acc1 = __builtin_amdgcn_mfma_f32_16x16x32_bf16(A0[kc], B11, acc1, 0, 0, 0);

// selection (packed-key med3 ladder), immediate on acc
#define SELECT(PACC, PS) { \
    const unsigned lidbase = (unsigned)((PS) << 4); \
    _Pragma("unroll") \
    for (int grp = 0; grp < 4; ++grp) { \
        f32x4 sq4 = *(const f32x4*)(sqs + (PS) * 32 + grp * 8 + kh * 4); \
        _Pragma("unroll") \
        for (int e = 0; e < 4; ++e) { \
            float dp = (sqi + sq4[e]) + (PACC)[grp * 4 + e]; \
            unsigned ku = (__float_as_uint(dp) & 0xFFFFFF00u) \
                        | (lidbase + (unsigned)(grp * 4 + e)); \
            float kk = __uint_as_float(ku); \
            bd[7] = __builtin_amdgcn_fmed3f(bd[6], kk, bd[7]); \
            bd[6] = __builtin_amdgcn_fmed3f(bd[5], kk, bd[6]); \
            bd[5] = __builtin_amdgcn_fmed3f(bd[4], kk, bd[5]); \
            bd[4] = __builtin_amdgcn_fmed3f(bd[3], kk, bd[4]); \
            bd[3] = __builtin_amdgcn_fmed3f(bd[2], kk, bd[3]); \
            bd[2] = __builtin_amdgcn_fmed3f(bd[1], kk, bd[2]); \
            bd[1] = __builtin_amdgcn_fmed3f(bd[0], kk, bd[1]); \
            bd[0] = fminf(bd[0], kk); \
        } \
    } }

#define KNN_MFMA_STEP(ACC) { \
    ACC = (f32x16){0.f,0.f,0.f,0.f,0.f,0.f,0.f,0.f,0.f,0.f,0.f,0.f,0.f,0.f,0.f,0.f}; \
    const char* pstep = ldsc + cur * 16384 + lane * 16; \
    __builtin_amdgcn_s_setprio(1); \
    _Pragma("unroll") \
    for (int kch = 0; kch < 8; ++kch) { \
        bf16x8 c0 = *(const bf16x8*)(pstep + kch * 1024); \
        bf16x8 c1 = *(const bf16x8*)(pstep + 8192 + kch * 1024); \
        ACC = __builtin_amdgcn_mfma_f32_32x32x16_bf16(c0, RB[0][kch], ACC, 0, 0, 0); \
        ACC = __builtin_amdgcn_mfma_f32_32x32x16_bf16(c1, RB[0][kch], ACC, 0, 0, 0); \
        ACC = __builtin_amdgcn_mfma_f32_32x32x16_bf16(c0, RB[1][kch], ACC, 0, 0, 0); \
    } \
    __builtin_amdgcn_s_setprio(0); }

// ---------------- fused: node_gemm (blocks 0-511) + kNN (blocks 512-1535) ----------------
// Round-17: single acc chain + immediate selection -> ~152 regs/wave -> 3 waves/SIMD.
__global__ __launch_bounds__(256, 3) void knn_node(const unsigned short* __restrict__ hs,
                                                   const float* __restrict__ sqg,
                                                   const unsigned short* __restrict__ Wt,
                                                   const float* __restrict__ ba,
                                                   float* __restrict__ P,
                                                   float* __restrict__ D,
                                                   float* __restrict__ cand_d)
{
    __shared__ ulong2 ldsraw[2176];   // 32KB dbuf + 2KB sq
    char* ldsc = (char*)ldsraw;
    const size_t plane = (size_t)NTOT * HD;
    const int t = threadIdx.x;
    const int wv = t >> 6, lane = t & 63;

    if (blockIdx.x < 512) {
        // ================= node GEMM =================
        const int lrow = lane & 15, kg = lane >> 4;
        const int nodebase = blockIdx.x * 64 + wv * 16;

        const unsigned short* arow = hs + (size_t)(nodebase + lrow) * HD + kg * 8;
        bf16x8 A0[4], A1[4];
#pragma unroll
        for (int kc = 0; kc < 4; ++kc) {
            A0[kc] = *(const bf16x8*)(arow + kc * 32);
            A1[kc] = *(const bf16x8*)(arow + plane + kc * 32);
        }

        char* ldsw = ldsc + wv * 1024;
        const unsigned short* wsrc = Wt + t * 8;
#pragma unroll
        for (int i = 0; i < 4; ++i)
            GLOAD_LDS16(wsrc + i * 2048, ldsw + i * 4096);
        __syncthreads();

        int cur = 0;
        for (int cs = 0; cs < 8; ++cs) {
            if (cs < 7) {
#pragma unroll
                for (int i = 0; i < 4; ++i)
                    GLOAD_LDS16(wsrc + (size_t)(cs + 1) * 12288 + i * 2048,
                                ldsc + (cur ^ 1) * 16384 + wv * 1024 + i * 4096);
            }
            const char* pb = ldsc + cur * 16384 + kg * 256 + lrow * 16;
            f32x4 acc0 = {0.f,0.f,0.f,0.f};
            f32x4 acc1 = {0.f,0.f,0.f,0.f};
#pragma unroll
            for (int kc = 0; kc < 4; ++kc) {
                const char* pk = pb + kc * 2048;
                bf16x8 b00 = *(const bf16x8*)(pk);
                bf16x8 b01 = *(const bf16x8*)(pk + 1024);
                bf16x8 b10 = *(const bf16x8*)(pk + 8192);
                bf16x8 b11 = *(const bf16x8*)(pk + 9216);
                THREEPASS(b00, b01, b10, b11)
            }
            int n0 = cs * 32 + lrow;
            if (cs < 4) {
#pragma unroll
                for (int r = 0; r < 4; ++r) {
                    size_t row = (size_t)(nodebase + kg * 4 + r) * HD;
                    P[row + n0]      = acc0[r];
                    P[row + n0 + 16] = acc1[r];
                }
            } else {
                float ba0 = ba[n0 - 128], ba1 = ba[n0 - 112];
#pragma unroll
                for (int r = 0; r < 4; ++r) {
                    size_t row = (size_t)(nodebase + kg * 4 + r) * HD;
                    D[row + n0 - 128] = acc0[r] + ba0;
                    D[row + n0 - 112] = acc1[r] + ba1;
                }
            }
            __syncthreads();
            cur ^= 1;
        }
        return;
    }

    // ================= kNN (4-way col split, single acc, immediate select) =================
    float* sqs = (float*)(ldsc + 32768);
    const int b = blockIdx.x - 512;     // 1024 knn blocks
    const int slot = b >> 3;
    const int g  = (b & 7) | ((slot & 1) << 3);
    const int rb = (slot >> 1) & 15;
    const int cs = (slot >> 5) & 3;
    const int gbase = g * NPG;
    const int cbase = cs * 512;
    const int rl = lane & 31, kh = lane >> 5;
    const int myrow = rb * 128 + wv * 32 + rl;

    sqs[t]       = sqg[gbase + cbase + t];
    sqs[t + 256] = sqg[gbase + cbase + 256 + t];

    bf16x8 RB[2][8];
    {
        const unsigned short* rrow = hs + (size_t)(gbase + myrow) * HD + kh * 8;
#pragma unroll
        for (int p = 0; p < 2; ++p)
#pragma unroll
            for (int kch = 0; kch < 8; ++kch) {
                bf16x8 v = *(const bf16x8*)(rrow + (size_t)p * plane + kch * 16);
                unsigned* u = (unsigned*)&v;
#pragma unroll
                for (int w = 0; w < 4; ++w)
                    u[w] = (u[w] + 0x00800080u) ^ 0x80008000u;
                RB[p][kch] = v;
            }
    }
    const float sqi = sqg[gbase + myrow];

    const unsigned short* sb = hs + (size_t)(gbase + cbase + (t & 31)) * HD
                             + (t >> 6) * 16 + ((t >> 5) & 1) * 8;

#pragma unroll
    for (int i = 0; i < 4; ++i)
        GLOAD_LDS16(sb + (size_t)(i >> 1) * plane + (i & 1) * 64,
                    ldsc + wv * 1024 + i * 4096);
    __syncthreads();

    const float INF = __uint_as_float(0x7F800000u);
    float bd[8];
#pragma unroll
    for (int s = 0; s < 8; ++s) bd[s] = INF;

    f32x16 acc;
    int cur = 0;
    for (int s = 0; s < 16; ++s) {
        if (s < 15) {
            const unsigned short* sbn = sb + (size_t)(s + 1) * 32 * HD;
#pragma unroll
            for (int i = 0; i < 4; ++i)
                GLOAD_LDS16(sbn + (size_t)(i >> 1) * plane + (i & 1) * 64,
                            ldsc + (cur ^ 1) * 16384 + wv * 1024 + i * 4096);
        }
        KNN_MFMA_STEP(acc)
        SELECT(acc, s)
        __syncthreads();
        cur ^= 1;
    }

    // re-encode as GLOBAL keys: (bits & ~0x7FF) | j, vectorized 2x float4 store
    const size_t ob = (size_t)(gbase + myrow) * 64 + cs * 16 + kh * 8;
    f32x4 o0, o1;
#pragma unroll
    for (int sel = 0; sel < 8; ++sel) {
        unsigned u = __float_as_uint(bd[sel]);
        unsigned lid = u & 255u;
        unsigned j = (unsigned)(cbase + (int)(lid >> 4) * 32 + (int)((lid >> 2) & 3u) * 8
                              + kh * 4 + (int)(lid & 3u));
        float kv = __uint_as_float((u & 0xFFFFF800u) | j);
        if (sel < 4) o0[sel] = kv; else o1[sel - 4] = kv;
    }
    *(f32x4*)(cand_d + ob)     = o0;
    *(f32x4*)(cand_d + ob + 4) = o1;
}

// ---------------- fused edge kernel: inline key-merge -> H1 -> GEMM2 -> max ----------------
template<bool FINAL>
__global__ __launch_bounds__(256) void edge_mlp(const float* __restrict__ P,
                                                const float* __restrict__ D,
                                                const float* __restrict__ cand_d,
                                                const unsigned short* __restrict__ Wbt,
                                                const float* __restrict__ bb,
                                                const float* __restrict__ w5,
                                                unsigned short* __restrict__ hsout,
                                                float* __restrict__ sqgout,
                                                float* __restrict__ out)
{
    __shared__ ulong2 ldsraw[2080];   // 32KB weights + 512B nbrs
    char* lds = (char*)ldsraw;
    int* nbrs = (int*)(lds + 32768);
    const size_t plane = (size_t)NTOT * HD;
    const int t = threadIdx.x, wv = t >> 6, lane = t & 63;
    const int lrow = lane & 15, kg = lane >> 4;
    const int node0 = blockIdx.x * 8;
    const int nodeA = node0 + wv * 2;

    char* ldsw = lds + wv * 1024;
    const unsigned short* wsrc = Wbt + t * 8;
    if (!FINAL) {
#pragma unroll
        for (int i = 0; i < 4; ++i)
            GLOAD_LDS16(wsrc + i * 2048, ldsw + i * 4096);
    }

    // wave 0: merge 8 sorted key-runs of 8 per row -> top-8 neighbor indices
    if (t < 64) {
        const int row = node0 + (t >> 3);
        const int run = t & 7;
        const int gb = (row >> 11) << 11;    // graph base
        const float* pd = cand_d + (size_t)row * 64 + run * 8;
        float d[8];
#pragma unroll
        for (int k = 0; k < 8; ++k) d[k] = pd[k];
        const float INF = __uint_as_float(0x7F800000u);
        float hd = d[0];
#pragma unroll
        for (int sel = 0; sel < 8; ++sel) {
            float md = hd;
#pragma unroll
            for (int m = 1; m < 8; m <<= 1)
                md = fminf(md, __shfl_xor(md, m, 8));
            if (run == sel)
                nbrs[(t >> 3) * 8 + sel] = gb + (int)(__float_as_uint(md) & 0x7FFu);
            bool win = (hd == md);     // keys unique -> exactly one winner
            if (win) {
                d[0]=d[1]; d[1]=d[2]; d[2]=d[3]; d[3]=d[4];
                d[4]=d[5]; d[5]=d[6]; d[6]=d[7]; d[7]=INF;
            }
            hd = d[0];
        }
    }
    __syncthreads();

    const int i_local = wv * 2 + (lrow >> 3);
    const int i_node = node0 + i_local;
    const int j = nbrs[i_local * 8 + (lrow & 7)];

    const float* dp = D + (size_t)i_node * HD + kg * 8;
    const float* pp = P + (size_t)j * HD + kg * 8;

    bf16x8 A0[4], A1[4];
    float sdot = 0.f;
#pragma unroll
    for (int kc = 0; kc < 4; ++kc) {
        float4 d0 = *(const float4*)(dp + kc * 32);
        float4 d1 = *(const float4*)(dp + kc * 32 + 4);
        float4 p0 = *(const float4*)(pp + kc * 32);
        float4 p1 = *(const float4*)(pp + kc * 32 + 4);
        float v[8];
        v[0]=fmaxf(d0.x+p0.x,0.f); v[1]=fmaxf(d0.y+p0.y,0.f);
        v[2]=fmaxf(d0.z+p0.z,0.f); v[3]=fmaxf(d0.w+p0.w,0.f);
        v[4]=fmaxf(d1.x+p1.x,0.f); v[5]=fmaxf(d1.y+p1.y,0.f);
        v[6]=fmaxf(d1.z+p1.z,0.f); v[7]=fmaxf(d1.w+p1.w,0.f);
        if (FINAL) {
#pragma unroll
            for (int e = 0; e < 8; ++e)
                sdot = fmaf(v[e], w5[kc * 32 + kg * 8 + e], sdot);
        } else {
#pragma unroll
            for (int e = 0; e < 8; ++e) {
                unsigned short b1 = bf16rn(v[e]); float r1 = v[e] - bf16tof(b1);
                unsigned short b2 = bf16rn(r1);
                A0[kc][e] = (short)b1; A1[kc][e] = (short)b2;
            }
        }
    }

    if (!FINAL) {
        const int mynode = nodeA + (kg >> 1);
        const bool writer = (kg & 1) == 0;
        float sqacc = 0.f;

        int cur = 0;
        for (int cs = 0; cs < 4; ++cs) {
            if (cs < 3) {
#pragma unroll
                for (int i = 0; i < 4; ++i)
                    GLOAD_LDS16(wsrc + (size_t)(cs + 1) * 12288 + i * 2048,
                                lds + (cur ^ 1) * 16384 + wv * 1024 + i * 4096);
            }
            const char* pb = lds + cur * 16384 + kg * 256 + lrow * 16;
            f32x4 acc0 = {0.f,0.f,0.f,0.f};
            f32x4 acc1 = {0.f,0.f,0.f,0.f};
#pragma unroll
            for (int kc = 0; kc < 4; ++kc) {
                const char* pk = pb + kc * 2048;
                bf16x8 b00 = *(const bf16x8*)(pk);
                bf16x8 b01 = *(const bf16x8*)(pk + 1024);
                bf16x8 b10 = *(const bf16x8*)(pk + 8192);
                bf16x8 b11 = *(const bf16x8*)(pk + 9216);
                THREEPASS(b00, b01, b10, b11)
            }
            float bb0 = bb[cs * 32 + lrow];
            float bb1 = bb[cs * 32 + 16 + lrow];
            float m0 = fmaxf(fmaxf(acc0[0], acc0[1]), fmaxf(acc0[2], acc0[3]));
            float m1 = fmaxf(fmaxf(acc1[0], acc1[1]), fmaxf(acc1[2], acc1[3]));
            m0 = fmaxf(m0 + bb0, 0.f);
            m1 = fmaxf(m1 + bb1, 0.f);
            m0 = fmaxf(m0, __shfl_xor(m0, 16));
            m1 = fmaxf(m1, __shfl_xor(m1, 16));
            if (writer) {
                sqacc = fmaf(m0, m0, fmaf(m1, m1, sqacc));
                size_t base = (size_t)mynode * HD + cs * 32 + lrow;
                unsigned short c1 = bf16rn(m0); float r1 = m0 - bf16tof(c1);
                unsigned short c2 = bf16rn(r1);
                hsout[base]         = c1;
                hsout[base + plane] = c2;
                unsigned short e1 = bf16rn(m1); float s1 = m1 - bf16tof(e1);
                unsigned short e2 = bf16rn(s1);
                hsout[base + 16]         = e1;
                hsout[base + 16 + plane] = e2;
            }
            __syncthreads();
            cur ^= 1;
        }
        if (writer) {
#pragma unroll
            for (int m = 1; m < 16; m <<= 1)
                sqacc += __shfl_xor(sqacc, m, 16);
            if (lrow == 0) sqgout[mynode] = sqacc;
        }
    } else {
        sdot += __shfl_xor(sdot, 16);
        sdot += __shfl_xor(sdot, 32);
        float s = fmaxf(sdot + bb[0], 0.f);
#pragma unroll
        for (int m = 1; m < 8; m <<= 1)
            s = fmaxf(s, __shfl_xor(s, m));
        if (lane == 0) out[nodeA]     = 1.f / (1.f + expf(-s));
        if (lane == 8) out[nodeA + 1] = 1.f / (1.f + expf(-s));
    }
}

extern "C" void kernel_launch(void* const* d_in, const int* in_sizes, int n_in,
                              void* d_out, int out_size, void* d_ws, size_t ws_size,
                              hipStream_t stream) {
    const float* x     = (const float*)d_in[0];
    const float* W_enc = (const float*)d_in[3];
    const float* b_enc = (const float*)d_in[4];
    const float* W1a = (const float*)d_in[5];
    const float* b1a = (const float*)d_in[6];
    const float* W1b = (const float*)d_in[7];
    const float* b1b = (const float*)d_in[8];
    const float* W2a = (const float*)d_in[9];
    const float* b2a = (const float*)d_in[10];
    const float* W2b = (const float*)d_in[11];
    const float* b2b = (const float*)d_in[12];
    const float* W5a = (const float*)d_in[13];
    const float* b5a = (const float*)d_in[14];
    const float* W5b = (const float*)d_in[15];
    const float* b5b = (const float*)d_in[16];

    unsigned short* hs = (unsigned short*)d_ws;                  // 16 MB (2 planes)
    float* sqg  = (float*)(hs + (size_t)2*NTOT*HD);              // 128 KB
    float* cd   = sqg + NTOT;                                    // 8 MB (packed keys)
    float* Dbuf = cd + (size_t)NTOT*64;                          // 16 MB
    float* Pbuf = Dbuf + (size_t)NTOT*HD;                        // 16 MB
    unsigned short* Wt1  = (unsigned short*)(Pbuf + (size_t)NTOT*HD);
    unsigned short* Wt2  = Wt1 + 98304;
    unsigned short* Wt5  = Wt2 + 98304;
    unsigned short* Wbt1 = Wt5 + 98304;
    unsigned short* Wbt2 = Wbt1 + 49152;

    setup_all<<<8704, 256, 0, stream>>>(x, W_enc, b_enc, hs, sqg,
                                        W1a, W2a, W5a, W1b, W2b,
                                        Wt1, Wt2, Wt5, Wbt1, Wbt2);

    // layer 1 (hs updated in place by edge_mlp)
    knn_node<<<1536, 256, 0, stream>>>(hs, sqg, Wt1, b1a, Pbuf, Dbuf, cd);
    edge_mlp<false><<<NTOT/8, 256, 0, stream>>>(Pbuf, Dbuf, cd, Wbt1, b1b, nullptr, hs, sqg, nullptr);

    // layer 2
    knn_node<<<1536, 256, 0, stream>>>(hs, sqg, Wt2, b2a, Pbuf, Dbuf, cd);
    edge_mlp<false><<<NTOT/8, 256, 0, stream>>>(Pbuf, Dbuf, cd, Wbt2, b2b, nullptr, hs, sqg, nullptr);

    // layer 5 (final)
    knn_node<<<1536, 256, 0, stream>>>(hs, sqg, Wt5, b5a, Pbuf, Dbuf, cd);
    edge_mlp<true><<<NTOT/8, 256, 0, stream>>>(Pbuf, Dbuf, cd, nullptr, b5b, W5b, nullptr, nullptr, (float*)d_out);
}

// Round 18
// 314.291 us; speedup vs baseline: 1.0462x; 1.0462x over previous
//
#include <hip/hip_runtime.h>
#include <hip/hip_bf16.h>
#include <math.h>

#define BGR 16
#define NPG 2048
#define HD  128
#define KNN 8
#define NTOT (BGR*NPG)   // 32768

using bf16x8 = __attribute__((ext_vector_type(8))) short;
using f32x4  = __attribute__((ext_vector_type(4))) float;
using f32x16 = __attribute__((ext_vector_type(16))) float;

typedef __attribute__((address_space(3))) unsigned int lds_uint;
typedef const __attribute__((address_space(1))) unsigned int glob_uint;
#define GLOAD_LDS16(g, l) __builtin_amdgcn_global_load_lds((glob_uint*)(g), (lds_uint*)(l), 16, 0, 0)

__device__ inline unsigned short bf16rn(float f) {
    unsigned u = __float_as_uint(f);
    unsigned r = (u + 0x7FFFu + ((u >> 16) & 1u)) >> 16;
    return (unsigned short)r;
}
__device__ inline float bf16tof(unsigned short h) {
    return __uint_as_float(((unsigned)h) << 16);
}

// ---------------- fused setup: encoder+split+sqnorm AND all weight prep ----------------
__device__ inline void wcat_body(const float* __restrict__ Wa,
                                 unsigned short* __restrict__ Wt, int lb, int t)
{
    int gid = lb * 256 + t;        // 32768 = 128k x 256n
    int k = gid >> 8, n = gid & 255;
    float w;
    if (n < 128) w = Wa[(128 + k) * 128 + n];
    else { int nn = n - 128; w = Wa[k * 128 + nn] - Wa[(128 + k) * 128 + nn]; }
    unsigned short b1 = bf16rn(w);  float r1 = w - bf16tof(b1);
    unsigned short b2 = bf16rn(r1);
    int cs = n >> 5, h = (n >> 4) & 1, c = n & 15, kc = k >> 5, kg = (k >> 3) & 3, e = k & 7;
    size_t off = (size_t)cs * 12288 + kc * 1024 + h * 512 + kg * 128 + c * 8 + e;
    Wt[off] = b1; Wt[off + 4096] = b2;
}

__device__ inline void wb_body(const float* __restrict__ Wb,
                               unsigned short* __restrict__ Wt, int lb, int t)
{
    int gid = lb * 256 + t;        // 16384 = 128k x 128n
    int k = gid >> 7, n = gid & 127;
    float w = Wb[k * 128 + n];
    unsigned short b1 = bf16rn(w);  float r1 = w - bf16tof(b1);
    unsigned short b2 = bf16rn(r1);
    int cs = n >> 5, h = (n >> 4) & 1, c = n & 15, kc = k >> 5, kg = (k >> 3) & 3, e = k & 7;
    size_t off = (size_t)cs * 12288 + kc * 1024 + h * 512 + kg * 128 + c * 8 + e;
    Wt[off] = b1; Wt[off + 4096] = b2;
}

__global__ __launch_bounds__(256) void setup_all(const float* __restrict__ x,
                                                 const float* __restrict__ We,
                                                 const float* __restrict__ be,
                                                 unsigned short* __restrict__ hs,
                                                 float* __restrict__ sqg,
                                                 const float* __restrict__ W1a,
                                                 const float* __restrict__ W2a,
                                                 const float* __restrict__ W5a,
                                                 const float* __restrict__ W1b,
                                                 const float* __restrict__ W2b,
                                                 unsigned short* __restrict__ Wt1,
                                                 unsigned short* __restrict__ Wt2,
                                                 unsigned short* __restrict__ Wt5,
                                                 unsigned short* __restrict__ Wbt1,
                                                 unsigned short* __restrict__ Wbt2)
{
    const int bb = blockIdx.x, t = threadIdx.x;
    if (bb < 8192) {
        const size_t plane = (size_t)NTOT * HD;
        int node = (bb * 256 + t) >> 6;
        int lane = t & 63;
        float4 xv = *(const float4*)(x + (size_t)node * 4);
        float v0 = be[lane], v1 = be[lane + 64];
        const float* xf = (const float*)&xv;
#pragma unroll
        for (int f = 0; f < 4; ++f) {
            v0 = fmaf(xf[f], We[f * 128 + lane], v0);
            v1 = fmaf(xf[f], We[f * 128 + lane + 64], v1);
        }
        float s = fmaf(v0, v0, v1 * v1);
#pragma unroll
        for (int off = 32; off >= 1; off >>= 1)
            s += __shfl_xor(s, off);
        if (lane == 0) sqg[node] = s;
#pragma unroll
        for (int q = 0; q < 2; ++q) {
            float v = q ? v1 : v0;
            int   d = lane + q * 64;
            unsigned short b1 = bf16rn(v);  float r1 = v - bf16tof(b1);
            unsigned short b2 = bf16rn(r1);
            size_t base = (size_t)node * HD + d;
            hs[base]         = b1;
            hs[base + plane] = b2;
        }
    }
    else if (bb < 8320) wcat_body(W1a, Wt1, bb - 8192, t);
    else if (bb < 8448) wcat_body(W2a, Wt2, bb - 8320, t);
    else if (bb < 8576) wcat_body(W5a, Wt5, bb - 8448, t);
    else if (bb < 8640) wb_body(W1b, Wbt1, bb - 8576, t);
    else                wb_body(W2b, Wbt2, bb - 8640, t);
}

// 3-pass: A0B0 + A1B0 + A0B1 (drop O(2^-16) A1B1 cross term)
#define THREEPASS(B00,B01,B10,B11) \
    acc0 = __builtin_amdgcn_mfma_f32_16x16x32_bf16(A0[kc], B00, acc0, 0, 0, 0); \
    acc1 = __builtin_amdgcn_mfma_f32_16x16x32_bf16(A0[kc], B01, acc1, 0, 0, 0); \
    acc0 = __builtin_amdgcn_mfma_f32_16x16x32_bf16(A1[kc], B00, acc0, 0, 0, 0); \
    acc1 = __builtin_amdgcn_mfma_f32_16x16x32_bf16(A1[kc], B01, acc1, 0, 0, 0); \
    acc0 = __builtin_amdgcn_mfma_f32_16x16x32_bf16(A0[kc], B10, acc0, 0, 0, 0); \
    acc1 = __builtin_amdgcn_mfma_f32_16x16x32_bf16(A0[kc], B11, acc1, 0, 0, 0);

// parameterized 3-pass for dual edge-groups
#define THREEPASS_G(AA0,AA1,B00,B01,B10,B11,C0,C1) \
    C0 = __builtin_amdgcn_mfma_f32_16x16x32_bf16(AA0[kc], B00, C0, 0, 0, 0); \
    C1 = __builtin_amdgcn_mfma_f32_16x16x32_bf16(AA0[kc], B01, C1, 0, 0, 0); \
    C0 = __builtin_amdgcn_mfma_f32_16x16x32_bf16(AA1[kc], B00, C0, 0, 0, 0); \
    C1 = __builtin_amdgcn_mfma_f32_16x16x32_bf16(AA1[kc], B01, C1, 0, 0, 0); \
    C0 = __builtin_amdgcn_mfma_f32_16x16x32_bf16(AA0[kc], B10, C0, 0, 0, 0); \
    C1 = __builtin_amdgcn_mfma_f32_16x16x32_bf16(AA0[kc], B11, C1, 0, 0, 0);

// selection (packed-key med3 ladder)
#define SELECT(PACC, PS) { \
    const unsigned lidbase = (unsigned)((PS) << 4); \
    _Pragma("unroll") \
    for (int grp = 0; grp < 4; ++grp) { \
        f32x4 sq4 = *(const f32x4*)(sqs + (PS) * 32 + grp * 8 + kh * 4); \
        _Pragma("unroll") \
        for (int e = 0; e < 4; ++e) { \
            float dp = (sqi + sq4[e]) + (PACC)[grp * 4 + e]; \
            unsigned ku = (__float_as_uint(dp) & 0xFFFFFF00u) \
                        | (lidbase + (unsigned)(grp * 4 + e)); \
            float kk = __uint_as_float(ku); \
            bd[7] = __builtin_amdgcn_fmed3f(bd[6], kk, bd[7]); \
            bd[6] = __builtin_amdgcn_fmed3f(bd[5], kk, bd[6]); \
            bd[5] = __builtin_amdgcn_fmed3f(bd[4], kk, bd[5]); \
            bd[4] = __builtin_amdgcn_fmed3f(bd[3], kk, bd[4]); \
            bd[3] = __builtin_amdgcn_fmed3f(bd[2], kk, bd[3]); \
            bd[2] = __builtin_amdgcn_fmed3f(bd[1], kk, bd[2]); \
            bd[1] = __builtin_amdgcn_fmed3f(bd[0], kk, bd[1]); \
            bd[0] = fminf(bd[0], kk); \
        } \
    } }

#define KNN_MFMA_STEP(ACC) { \
    ACC = (f32x16){0.f,0.f,0.f,0.f,0.f,0.f,0.f,0.f,0.f,0.f,0.f,0.f,0.f,0.f,0.f,0.f}; \
    const char* pstep = ldsc + cur * 16384 + lane * 16; \
    __builtin_amdgcn_s_setprio(1); \
    _Pragma("unroll") \
    for (int kch = 0; kch < 8; ++kch) { \
        bf16x8 c0 = *(const bf16x8*)(pstep + kch * 1024); \
        bf16x8 c1 = *(const bf16x8*)(pstep + 8192 + kch * 1024); \
        ACC = __builtin_amdgcn_mfma_f32_32x32x16_bf16(c0, RB[0][kch], ACC, 0, 0, 0); \
        ACC = __builtin_amdgcn_mfma_f32_32x32x16_bf16(c1, RB[0][kch], ACC, 0, 0, 0); \
        ACC = __builtin_amdgcn_mfma_f32_32x32x16_bf16(c0, RB[1][kch], ACC, 0, 0, 0); \
    } \
    __builtin_amdgcn_s_setprio(0); }

// ---------------- fused: node_gemm (blocks 0-511) + kNN (blocks 512-1535) ----------------
__global__ __launch_bounds__(256, 3) void knn_node(const unsigned short* __restrict__ hs,
                                                   const float* __restrict__ sqg,
                                                   const unsigned short* __restrict__ Wt,
                                                   const float* __restrict__ ba,
                                                   float* __restrict__ P,
                                                   float* __restrict__ D,
                                                   float* __restrict__ cand_d)
{
    __shared__ ulong2 ldsraw[2176];   // 32KB dbuf + 2KB sq
    char* ldsc = (char*)ldsraw;
    const size_t plane = (size_t)NTOT * HD;
    const int t = threadIdx.x;
    const int wv = t >> 6, lane = t & 63;

    if (blockIdx.x < 512) {
        // ================= node GEMM =================
        const int lrow = lane & 15, kg = lane >> 4;
        const int nodebase = blockIdx.x * 64 + wv * 16;

        const unsigned short* arow = hs + (size_t)(nodebase + lrow) * HD + kg * 8;
        bf16x8 A0[4], A1[4];
#pragma unroll
        for (int kc = 0; kc < 4; ++kc) {
            A0[kc] = *(const bf16x8*)(arow + kc * 32);
            A1[kc] = *(const bf16x8*)(arow + plane + kc * 32);
        }

        char* ldsw = ldsc + wv * 1024;
        const unsigned short* wsrc = Wt + t * 8;
#pragma unroll
        for (int i = 0; i < 4; ++i)
            GLOAD_LDS16(wsrc + i * 2048, ldsw + i * 4096);
        __syncthreads();

        int cur = 0;
        for (int cs = 0; cs < 8; ++cs) {
            if (cs < 7) {
#pragma unroll
                for (int i = 0; i < 4; ++i)
                    GLOAD_LDS16(wsrc + (size_t)(cs + 1) * 12288 + i * 2048,
                                ldsc + (cur ^ 1) * 16384 + wv * 1024 + i * 4096);
            }
            const char* pb = ldsc + cur * 16384 + kg * 256 + lrow * 16;
            f32x4 acc0 = {0.f,0.f,0.f,0.f};
            f32x4 acc1 = {0.f,0.f,0.f,0.f};
#pragma unroll
            for (int kc = 0; kc < 4; ++kc) {
                const char* pk = pb + kc * 2048;
                bf16x8 b00 = *(const bf16x8*)(pk);
                bf16x8 b01 = *(const bf16x8*)(pk + 1024);
                bf16x8 b10 = *(const bf16x8*)(pk + 8192);
                bf16x8 b11 = *(const bf16x8*)(pk + 9216);
                THREEPASS(b00, b01, b10, b11)
            }
            int n0 = cs * 32 + lrow;
            if (cs < 4) {
#pragma unroll
                for (int r = 0; r < 4; ++r) {
                    size_t row = (size_t)(nodebase + kg * 4 + r) * HD;
                    P[row + n0]      = acc0[r];
                    P[row + n0 + 16] = acc1[r];
                }
            } else {
                float ba0 = ba[n0 - 128], ba1 = ba[n0 - 112];
#pragma unroll
                for (int r = 0; r < 4; ++r) {
                    size_t row = (size_t)(nodebase + kg * 4 + r) * HD;
                    D[row + n0 - 128] = acc0[r] + ba0;
                    D[row + n0 - 112] = acc1[r] + ba1;
                }
            }
            __syncthreads();
            cur ^= 1;
        }
        return;
    }

    // ================= kNN (4-way col split, single acc, immediate select) =================
    float* sqs = (float*)(ldsc + 32768);
    const int b = blockIdx.x - 512;     // 1024 knn blocks
    const int slot = b >> 3;
    const int g  = (b & 7) | ((slot & 1) << 3);
    const int rb = (slot >> 1) & 15;
    const int cs = (slot >> 5) & 3;
    const int gbase = g * NPG;
    const int cbase = cs * 512;
    const int rl = lane & 31, kh = lane >> 5;
    const int myrow = rb * 128 + wv * 32 + rl;

    sqs[t]       = sqg[gbase + cbase + t];
    sqs[t + 256] = sqg[gbase + cbase + 256 + t];

    bf16x8 RB[2][8];
    {
        const unsigned short* rrow = hs + (size_t)(gbase + myrow) * HD + kh * 8;
#pragma unroll
        for (int p = 0; p < 2; ++p)
#pragma unroll
            for (int kch = 0; kch < 8; ++kch) {
                bf16x8 v = *(const bf16x8*)(rrow + (size_t)p * plane + kch * 16);
                unsigned* u = (unsigned*)&v;
#pragma unroll
                for (int w = 0; w < 4; ++w)
                    u[w] = (u[w] + 0x00800080u) ^ 0x80008000u;
                RB[p][kch] = v;
            }
    }
    const float sqi = sqg[gbase + myrow];

    const unsigned short* sb = hs + (size_t)(gbase + cbase + (t & 31)) * HD
                             + (t >> 6) * 16 + ((t >> 5) & 1) * 8;

#pragma unroll
    for (int i = 0; i < 4; ++i)
        GLOAD_LDS16(sb + (size_t)(i >> 1) * plane + (i & 1) * 64,
                    ldsc + wv * 1024 + i * 4096);
    __syncthreads();

    const float INF = __uint_as_float(0x7F800000u);
    float bd[8];
#pragma unroll
    for (int s = 0; s < 8; ++s) bd[s] = INF;

    f32x16 acc;
    int cur = 0;
    for (int s = 0; s < 16; ++s) {
        if (s < 15) {
            const unsigned short* sbn = sb + (size_t)(s + 1) * 32 * HD;
#pragma unroll
            for (int i = 0; i < 4; ++i)
                GLOAD_LDS16(sbn + (size_t)(i >> 1) * plane + (i & 1) * 64,
                            ldsc + (cur ^ 1) * 16384 + wv * 1024 + i * 4096);
        }
        KNN_MFMA_STEP(acc)
        SELECT(acc, s)
        __syncthreads();
        cur ^= 1;
    }

    // re-encode as GLOBAL keys: (bits & ~0x7FF) | j, vectorized 2x float4 store
    const size_t ob = (size_t)(gbase + myrow) * 64 + cs * 16 + kh * 8;
    f32x4 o0, o1;
#pragma unroll
    for (int sel = 0; sel < 8; ++sel) {
        unsigned u = __float_as_uint(bd[sel]);
        unsigned lid = u & 255u;
        unsigned j = (unsigned)(cbase + (int)(lid >> 4) * 32 + (int)((lid >> 2) & 3u) * 8
                              + kh * 4 + (int)(lid & 3u));
        float kv = __uint_as_float((u & 0xFFFFF800u) | j);
        if (sel < 4) o0[sel] = kv; else o1[sel - 4] = kv;
    }
    *(f32x4*)(cand_d + ob)     = o0;
    *(f32x4*)(cand_d + ob + 4) = o1;
}

// ---------------- fused edge kernel: 16 nodes/block, dual edge-groups/wave ----------------
template<bool FINAL>
__global__ __launch_bounds__(256) void edge_mlp(const float* __restrict__ P,
                                                const float* __restrict__ D,
                                                const float* __restrict__ cand_d,
                                                const unsigned short* __restrict__ Wbt,
                                                const float* __restrict__ bb,
                                                const float* __restrict__ w5,
                                                unsigned short* __restrict__ hsout,
                                                float* __restrict__ sqgout,
                                                float* __restrict__ out)
{
    __shared__ ulong2 ldsraw[2112];   // 32KB weights + 512B nbrs
    char* lds = (char*)ldsraw;
    int* nbrs = (int*)(lds + 32768);
    const size_t plane = (size_t)NTOT * HD;
    const int t = threadIdx.x, wv = t >> 6, lane = t & 63;
    const int lrow = lane & 15, kg = lane >> 4;
    const int node0 = blockIdx.x * 16;
    const int bn = node0 + wv * 4;     // wave's 4 nodes

    char* ldsw = lds + wv * 1024;
    const unsigned short* wsrc = Wbt + t * 8;
    if (!FINAL) {
#pragma unroll
        for (int i = 0; i < 4; ++i)
            GLOAD_LDS16(wsrc + i * 2048, ldsw + i * 4096);
    }

    // t<128: merge 16 rows' 8 sorted key-runs -> top-8 neighbor indices
    if (t < 128) {
        const int row = node0 + (t >> 3);
        const int run = t & 7;
        const int gb = (row >> 11) << 11;    // graph base
        const float* pd = cand_d + (size_t)row * 64 + run * 8;
        float d[8];
#pragma unroll
        for (int k = 0; k < 8; ++k) d[k] = pd[k];
        const float INF = __uint_as_float(0x7F800000u);
        float hd = d[0];
#pragma unroll
        for (int sel = 0; sel < 8; ++sel) {
            float md = hd;
#pragma unroll
            for (int m = 1; m < 8; m <<= 1)
                md = fminf(md, __shfl_xor(md, m, 8));
            if (run == sel)
                nbrs[(t >> 3) * 8 + sel] = gb + (int)(__float_as_uint(md) & 0x7FFu);
            bool win = (hd == md);     // keys unique -> exactly one winner
            if (win) {
                d[0]=d[1]; d[1]=d[2]; d[2]=d[3]; d[3]=d[4];
                d[4]=d[5]; d[5]=d[6]; d[6]=d[7]; d[7]=INF;
            }
            hd = d[0];
        }
    }
    __syncthreads();

    const int en = lrow >> 3;          // node within pair
    const int ee = lrow & 7;           // edge within node
    const int i0 = bn + en;            // group-a node
    const int i1 = bn + 2 + en;        // group-b node
    const int j0 = nbrs[(wv * 4 + en) * 8 + ee];
    const int j1 = nbrs[(wv * 4 + 2 + en) * 8 + ee];

    const float* dp0 = D + (size_t)i0 * HD + kg * 8;
    const float* pp0 = P + (size_t)j0 * HD + kg * 8;
    const float* dp1 = D + (size_t)i1 * HD + kg * 8;
    const float* pp1 = P + (size_t)j1 * HD + kg * 8;

    bf16x8 A0a[4], A1a[4], A0b[4], A1b[4];
    float sdot0 = 0.f, sdot1 = 0.f;
#pragma unroll
    for (int kc = 0; kc < 4; ++kc) {
#pragma unroll
        for (int gsel = 0; gsel < 2; ++gsel) {
            const float* dpx = gsel ? dp1 : dp0;
            const float* ppx = gsel ? pp1 : pp0;
            float4 d0 = *(const float4*)(dpx + kc * 32);
            float4 d1 = *(const float4*)(dpx + kc * 32 + 4);
            float4 p0 = *(const float4*)(ppx + kc * 32);
            float4 p1 = *(const float4*)(ppx + kc * 32 + 4);
            float v[8];
            v[0]=fmaxf(d0.x+p0.x,0.f); v[1]=fmaxf(d0.y+p0.y,0.f);
            v[2]=fmaxf(d0.z+p0.z,0.f); v[3]=fmaxf(d0.w+p0.w,0.f);
            v[4]=fmaxf(d1.x+p1.x,0.f); v[5]=fmaxf(d1.y+p1.y,0.f);
            v[6]=fmaxf(d1.z+p1.z,0.f); v[7]=fmaxf(d1.w+p1.w,0.f);
            if (FINAL) {
                float s = 0.f;
#pragma unroll
                for (int e = 0; e < 8; ++e)
                    s = fmaf(v[e], w5[kc * 32 + kg * 8 + e], s);
                if (gsel) sdot1 += s; else sdot0 += s;
            } else {
#pragma unroll
                for (int e = 0; e < 8; ++e) {
                    unsigned short b1 = bf16rn(v[e]); float r1 = v[e] - bf16tof(b1);
                    unsigned short b2 = bf16rn(r1);
                    if (gsel) { A0b[kc][e] = (short)b1; A1b[kc][e] = (short)b2; }
                    else      { A0a[kc][e] = (short)b1; A1a[kc][e] = (short)b2; }
                }
            }
        }
    }

    if (!FINAL) {
        const bool writer = (kg & 1) == 0;
        const int mn0 = bn + (kg >> 1);
        const int mn1 = bn + 2 + (kg >> 1);
        float sqacc0 = 0.f, sqacc1 = 0.f;

        int cur = 0;
        for (int cs = 0; cs < 4; ++cs) {
            if (cs < 3) {
#pragma unroll
                for (int i = 0; i < 4; ++i)
                    GLOAD_LDS16(wsrc + (size_t)(cs + 1) * 12288 + i * 2048,
                                lds + (cur ^ 1) * 16384 + wv * 1024 + i * 4096);
            }
            const char* pb = lds + cur * 16384 + kg * 256 + lrow * 16;
            f32x4 acc0a = {0.f,0.f,0.f,0.f}, acc1a = {0.f,0.f,0.f,0.f};
            f32x4 acc0b = {0.f,0.f,0.f,0.f}, acc1b = {0.f,0.f,0.f,0.f};
#pragma unroll
            for (int kc = 0; kc < 4; ++kc) {
                const char* pk = pb + kc * 2048;
                bf16x8 b00 = *(const bf16x8*)(pk);
                bf16x8 b01 = *(const bf16x8*)(pk + 1024);
                bf16x8 b10 = *(const bf16x8*)(pk + 8192);
                bf16x8 b11 = *(const bf16x8*)(pk + 9216);
                THREEPASS_G(A0a, A1a, b00, b01, b10, b11, acc0a, acc1a)
                THREEPASS_G(A0b, A1b, b00, b01, b10, b11, acc0b, acc1b)
            }
            float bb0 = bb[cs * 32 + lrow];
            float bb1 = bb[cs * 32 + 16 + lrow];
            // group a
            {
                float m0 = fmaxf(fmaxf(acc0a[0], acc0a[1]), fmaxf(acc0a[2], acc0a[3]));
                float m1 = fmaxf(fmaxf(acc1a[0], acc1a[1]), fmaxf(acc1a[2], acc1a[3]));
                m0 = fmaxf(m0 + bb0, 0.f);
                m1 = fmaxf(m1 + bb1, 0.f);
                m0 = fmaxf(m0, __shfl_xor(m0, 16));
                m1 = fmaxf(m1, __shfl_xor(m1, 16));
                if (writer) {
                    sqacc0 = fmaf(m0, m0, fmaf(m1, m1, sqacc0));
                    size_t base = (size_t)mn0 * HD + cs * 32 + lrow;
                    unsigned short c1 = bf16rn(m0); float r1 = m0 - bf16tof(c1);
                    unsigned short c2 = bf16rn(r1);
                    hsout[base]         = c1;
                    hsout[base + plane] = c2;
                    unsigned short e1 = bf16rn(m1); float s1 = m1 - bf16tof(e1);
                    unsigned short e2 = bf16rn(s1);
                    hsout[base + 16]         = e1;
                    hsout[base + 16 + plane] = e2;
                }
            }
            // group b
            {
                float m0 = fmaxf(fmaxf(acc0b[0], acc0b[1]), fmaxf(acc0b[2], acc0b[3]));
                float m1 = fmaxf(fmaxf(acc1b[0], acc1b[1]), fmaxf(acc1b[2], acc1b[3]));
                m0 = fmaxf(m0 + bb0, 0.f);
                m1 = fmaxf(m1 + bb1, 0.f);
                m0 = fmaxf(m0, __shfl_xor(m0, 16));
                m1 = fmaxf(m1, __shfl_xor(m1, 16));
                if (writer) {
                    sqacc1 = fmaf(m0, m0, fmaf(m1, m1, sqacc1));
                    size_t base = (size_t)mn1 * HD + cs * 32 + lrow;
                    unsigned short c1 = bf16rn(m0); float r1 = m0 - bf16tof(c1);
                    unsigned short c2 = bf16rn(r1);
                    hsout[base]         = c1;
                    hsout[base + plane] = c2;
                    unsigned short e1 = bf16rn(m1); float s1 = m1 - bf16tof(e1);
                    unsigned short e2 = bf16rn(s1);
                    hsout[base + 16]         = e1;
                    hsout[base + 16 + plane] = e2;
                }
            }
            __syncthreads();
            cur ^= 1;
        }
        if (writer) {
#pragma unroll
            for (int m = 1; m < 16; m <<= 1) {
                sqacc0 += __shfl_xor(sqacc0, m, 16);
                sqacc1 += __shfl_xor(sqacc1, m, 16);
            }
            if (lrow == 0) {
                sqgout[mn0] = sqacc0;
                sqgout[mn1] = sqacc1;
            }
        }
    } else {
        sdot0 += __shfl_xor(sdot0, 16);
        sdot0 += __shfl_xor(sdot0, 32);
        sdot1 += __shfl_xor(sdot1, 16);
        sdot1 += __shfl_xor(sdot1, 32);
        float s0 = fmaxf(sdot0 + bb[0], 0.f);
        float s1 = fmaxf(sdot1 + bb[0], 0.f);
#pragma unroll
        for (int m = 1; m < 8; m <<= 1) {
            s0 = fmaxf(s0, __shfl_xor(s0, m));
            s1 = fmaxf(s1, __shfl_xor(s1, m));
        }
        if (lane == 0) {
            out[bn]     = 1.f / (1.f + expf(-s0));
            out[bn + 2] = 1.f / (1.f + expf(-s1));
        }
        if (lane == 8) {
            out[bn + 1] = 1.f / (1.f + expf(-s0));
            out[bn + 3] = 1.f / (1.f + expf(-s1));
        }
    }
}

extern "C" void kernel_launch(void* const* d_in, const int* in_sizes, int n_in,
                              void* d_out, int out_size, void* d_ws, size_t ws_size,
                              hipStream_t stream) {
    const float* x     = (const float*)d_in[0];
    const float* W_enc = (const float*)d_in[3];
    const float* b_enc = (const float*)d_in[4];
    const float* W1a = (const float*)d_in[5];
    const float* b1a = (const float*)d_in[6];
    const float* W1b = (const float*)d_in[7];
    const float* b1b = (const float*)d_in[8];
    const float* W2a = (const float*)d_in[9];
    const float* b2a = (const float*)d_in[10];
    const float* W2b = (const float*)d_in[11];
    const float* b2b = (const float*)d_in[12];
    const float* W5a = (const float*)d_in[13];
    const float* b5a = (const float*)d_in[14];
    const float* W5b = (const float*)d_in[15];
    const float* b5b = (const float*)d_in[16];

    unsigned short* hs = (unsigned short*)d_ws;                  // 16 MB (2 planes)
    float* sqg  = (float*)(hs + (size_t)2*NTOT*HD);              // 128 KB
    float* cd   = sqg + NTOT;                                    // 8 MB (packed keys)
    float* Dbuf = cd + (size_t)NTOT*64;                          // 16 MB
    float* Pbuf = Dbuf + (size_t)NTOT*HD;                        // 16 MB
    unsigned short* Wt1  = (unsigned short*)(Pbuf + (size_t)NTOT*HD);
    unsigned short* Wt2  = Wt1 + 98304;
    unsigned short* Wt5  = Wt2 + 98304;
    unsigned short* Wbt1 = Wt5 + 98304;
    unsigned short* Wbt2 = Wbt1 + 49152;

    setup_all<<<8704, 256, 0, stream>>>(x, W_enc, b_enc, hs, sqg,
                                        W1a, W2a, W5a, W1b, W2b,
                                        Wt1, Wt2, Wt5, Wbt1, Wbt2);

    // layer 1 (hs updated in place by edge_mlp)
    knn_node<<<1536, 256, 0, stream>>>(hs, sqg, Wt1, b1a, Pbuf, Dbuf, cd);
    edge_mlp<false><<<NTOT/16, 256, 0, stream>>>(Pbuf, Dbuf, cd, Wbt1, b1b, nullptr, hs, sqg, nullptr);

    // layer 2
    knn_node<<<1536, 256, 0, stream>>>(hs, sqg, Wt2, b2a, Pbuf, Dbuf, cd);
    edge_mlp<false><<<NTOT/16, 256, 0, stream>>>(Pbuf, Dbuf, cd, Wbt2, b2b, nullptr, hs, sqg, nullptr);

    // layer 5 (final)
    knn_node<<<1536, 256, 0, stream>>>(hs, sqg, Wt5, b5a, Pbuf, Dbuf, cd);
    edge_mlp<true><<<NTOT/16, 256, 0, stream>>>(Pbuf, Dbuf, cd, nullptr, b5b, W5b, nullptr, nullptr, (float*)d_out);
}

// Round 19
// 311.847 us; speedup vs baseline: 1.0544x; 1.0078x over previous
//
#include <hip/hip_runtime.h>
#include <hip/hip_bf16.h>
#include <math.h>

#define BGR 16
#define NPG 2048
#define HD  128
#define KNN 8
#define NTOT (BGR*NPG)   // 32768

using bf16x8 = __attribute__((ext_vector_type(8))) short;
using f32x4  = __attribute__((ext_vector_type(4))) float;
using f32x16 = __attribute__((ext_vector_type(16))) float;

typedef __attribute__((address_space(3))) unsigned int lds_uint;
typedef const __attribute__((address_space(1))) unsigned int glob_uint;
#define GLOAD_LDS16(g, l) __builtin_amdgcn_global_load_lds((glob_uint*)(g), (lds_uint*)(l), 16, 0, 0)

__device__ inline unsigned short bf16rn(float f) {
    unsigned u = __float_as_uint(f);
    unsigned r = (u + 0x7FFFu + ((u >> 16) & 1u)) >> 16;
    return (unsigned short)r;
}
__device__ inline float bf16tof(unsigned short h) {
    return __uint_as_float(((unsigned)h) << 16);
}

// ---------------- fused setup: encoder+split+sqnorm AND all weight prep ----------------
__device__ inline void wcat_body(const float* __restrict__ Wa,
                                 unsigned short* __restrict__ Wt, int lb, int t)
{
    int gid = lb * 256 + t;        // 32768 = 128k x 256n
    int k = gid >> 8, n = gid & 255;
    float w;
    if (n < 128) w = Wa[(128 + k) * 128 + n];
    else { int nn = n - 128; w = Wa[k * 128 + nn] - Wa[(128 + k) * 128 + nn]; }
    unsigned short b1 = bf16rn(w);  float r1 = w - bf16tof(b1);
    unsigned short b2 = bf16rn(r1);
    int cs = n >> 5, h = (n >> 4) & 1, c = n & 15, kc = k >> 5, kg = (k >> 3) & 3, e = k & 7;
    size_t off = (size_t)cs * 12288 + kc * 1024 + h * 512 + kg * 128 + c * 8 + e;
    Wt[off] = b1; Wt[off + 4096] = b2;
}

__device__ inline void wb_body(const float* __restrict__ Wb,
                               unsigned short* __restrict__ Wt, int lb, int t)
{
    int gid = lb * 256 + t;        // 16384 = 128k x 128n
    int k = gid >> 7, n = gid & 127;
    float w = Wb[k * 128 + n];
    unsigned short b1 = bf16rn(w);  float r1 = w - bf16tof(b1);
    unsigned short b2 = bf16rn(r1);
    int cs = n >> 5, h = (n >> 4) & 1, c = n & 15, kc = k >> 5, kg = (k >> 3) & 3, e = k & 7;
    size_t off = (size_t)cs * 12288 + kc * 1024 + h * 512 + kg * 128 + c * 8 + e;
    Wt[off] = b1; Wt[off + 4096] = b2;
}

__global__ __launch_bounds__(256) void setup_all(const float* __restrict__ x,
                                                 const float* __restrict__ We,
                                                 const float* __restrict__ be,
                                                 unsigned short* __restrict__ hs,
                                                 float* __restrict__ sqg,
                                                 const float* __restrict__ W1a,
                                                 const float* __restrict__ W2a,
                                                 const float* __restrict__ W5a,
                                                 const float* __restrict__ W1b,
                                                 const float* __restrict__ W2b,
                                                 unsigned short* __restrict__ Wt1,
                                                 unsigned short* __restrict__ Wt2,
                                                 unsigned short* __restrict__ Wt5,
                                                 unsigned short* __restrict__ Wbt1,
                                                 unsigned short* __restrict__ Wbt2)
{
    const int bb = blockIdx.x, t = threadIdx.x;
    if (bb < 8192) {
        const size_t plane = (size_t)NTOT * HD;
        int node = (bb * 256 + t) >> 6;
        int lane = t & 63;
        float4 xv = *(const float4*)(x + (size_t)node * 4);
        float v0 = be[lane], v1 = be[lane + 64];
        const float* xf = (const float*)&xv;
#pragma unroll
        for (int f = 0; f < 4; ++f) {
            v0 = fmaf(xf[f], We[f * 128 + lane], v0);
            v1 = fmaf(xf[f], We[f * 128 + lane + 64], v1);
        }
        float s = fmaf(v0, v0, v1 * v1);
#pragma unroll
        for (int off = 32; off >= 1; off >>= 1)
            s += __shfl_xor(s, off);
        if (lane == 0) sqg[node] = s;
#pragma unroll
        for (int q = 0; q < 2; ++q) {
            float v = q ? v1 : v0;
            int   d = lane + q * 64;
            unsigned short b1 = bf16rn(v);  float r1 = v - bf16tof(b1);
            unsigned short b2 = bf16rn(r1);
            size_t base = (size_t)node * HD + d;
            hs[base]         = b1;
            hs[base + plane] = b2;
        }
    }
    else if (bb < 8320) wcat_body(W1a, Wt1, bb - 8192, t);
    else if (bb < 8448) wcat_body(W2a, Wt2, bb - 8320, t);
    else if (bb < 8576) wcat_body(W5a, Wt5, bb - 8448, t);
    else if (bb < 8640) wb_body(W1b, Wbt1, bb - 8576, t);
    else                wb_body(W2b, Wbt2, bb - 8640, t);
}

// 3-pass: A0B0 + A1B0 + A0B1 (drop O(2^-16) A1B1 cross term)
#define THREEPASS(B00,B01,B10,B11) \
    acc0 = __builtin_amdgcn_mfma_f32_16x16x32_bf16(A0[kc], B00, acc0, 0, 0, 0); \
    acc1 = __builtin_amdgcn_mfma_f32_16x16x32_bf16(A0[kc], B01, acc1, 0, 0, 0); \
    acc0 = __builtin_amdgcn_mfma_f32_16x16x32_bf16(A1[kc], B00, acc0, 0, 0, 0); \
    acc1 = __builtin_amdgcn_mfma_f32_16x16x32_bf16(A1[kc], B01, acc1, 0, 0, 0); \
    acc0 = __builtin_amdgcn_mfma_f32_16x16x32_bf16(A0[kc], B10, acc0, 0, 0, 0); \
    acc1 = __builtin_amdgcn_mfma_f32_16x16x32_bf16(A0[kc], B11, acc1, 0, 0, 0);

// parameterized 3-pass for dual edge-groups
#define THREEPASS_G(AA0,AA1,B00,B01,B10,B11,C0,C1) \
    C0 = __builtin_amdgcn_mfma_f32_16x16x32_bf16(AA0[kc], B00, C0, 0, 0, 0); \
    C1 = __builtin_amdgcn_mfma_f32_16x16x32_bf16(AA0[kc], B01, C1, 0, 0, 0); \
    C0 = __builtin_amdgcn_mfma_f32_16x16x32_bf16(AA1[kc], B00, C0, 0, 0, 0); \
    C1 = __builtin_amdgcn_mfma_f32_16x16x32_bf16(AA1[kc], B01, C1, 0, 0, 0); \
    C0 = __builtin_amdgcn_mfma_f32_16x16x32_bf16(AA0[kc], B10, C0, 0, 0, 0); \
    C1 = __builtin_amdgcn_mfma_f32_16x16x32_bf16(AA0[kc], B11, C1, 0, 0, 0);

// selection: acc already holds sqj - 2*dot (sqj folded into MFMA C-init); key = pack(acc)
#define SELECT(PACC, PS) { \
    const unsigned lidbase = (unsigned)((PS) << 4); \
    _Pragma("unroll") \
    for (int i = 0; i < 16; ++i) { \
        unsigned ku = (__float_as_uint((PACC)[i]) & 0xFFFFFF00u) \
                    | (lidbase + (unsigned)i); \
        float kk = __uint_as_float(ku); \
        bd[7] = __builtin_amdgcn_fmed3f(bd[6], kk, bd[7]); \
        bd[6] = __builtin_amdgcn_fmed3f(bd[5], kk, bd[6]); \
        bd[5] = __builtin_amdgcn_fmed3f(bd[4], kk, bd[5]); \
        bd[4] = __builtin_amdgcn_fmed3f(bd[3], kk, bd[4]); \
        bd[3] = __builtin_amdgcn_fmed3f(bd[2], kk, bd[2] > bd[3] ? bd[2] : bd[3]); \
        bd[3] = __builtin_amdgcn_fmed3f(bd[2], kk, bd[3]); \
        bd[2] = __builtin_amdgcn_fmed3f(bd[1], kk, bd[2]); \
        bd[1] = __builtin_amdgcn_fmed3f(bd[0], kk, bd[1]); \
        bd[0] = fminf(bd[0], kk); \
    } }

// (clean version without the stray line above)
#undef SELECT
#define SELECT(PACC, PS) { \
    const unsigned lidbase = (unsigned)((PS) << 4); \
    _Pragma("unroll") \
    for (int i = 0; i < 16; ++i) { \
        unsigned ku = (__float_as_uint((PACC)[i]) & 0xFFFFFF00u) \
                    | (lidbase + (unsigned)i); \
        float kk = __uint_as_float(ku); \
        bd[7] = __builtin_amdgcn_fmed3f(bd[6], kk, bd[7]); \
        bd[6] = __builtin_amdgcn_fmed3f(bd[5], kk, bd[6]); \
        bd[5] = __builtin_amdgcn_fmed3f(bd[4], kk, bd[5]); \
        bd[4] = __builtin_amdgcn_fmed3f(bd[3], kk, bd[4]); \
        bd[3] = __builtin_amdgcn_fmed3f(bd[2], kk, bd[3]); \
        bd[2] = __builtin_amdgcn_fmed3f(bd[1], kk, bd[2]); \
        bd[1] = __builtin_amdgcn_fmed3f(bd[0], kk, bd[1]); \
        bd[0] = fminf(bd[0], kk); \
    } }

// MFMA step with C initialized to sqj (per-element column norm)
#define KNN_MFMA_STEP(ACC, S) { \
    const float* qq = sqs + (S) * 32 + kh * 4; \
    f32x4 q0 = *(const f32x4*)(qq); \
    f32x4 q1 = *(const f32x4*)(qq + 8); \
    f32x4 q2 = *(const f32x4*)(qq + 16); \
    f32x4 q3 = *(const f32x4*)(qq + 24); \
    ACC[0]=q0[0]; ACC[1]=q0[1]; ACC[2]=q0[2]; ACC[3]=q0[3]; \
    ACC[4]=q1[0]; ACC[5]=q1[1]; ACC[6]=q1[2]; ACC[7]=q1[3]; \
    ACC[8]=q2[0]; ACC[9]=q2[1]; ACC[10]=q2[2]; ACC[11]=q2[3]; \
    ACC[12]=q3[0]; ACC[13]=q3[1]; ACC[14]=q3[2]; ACC[15]=q3[3]; \
    const char* pstep = ldsc + cur * 16384 + lane * 16; \
    __builtin_amdgcn_s_setprio(1); \
    _Pragma("unroll") \
    for (int kch = 0; kch < 8; ++kch) { \
        bf16x8 c0 = *(const bf16x8*)(pstep + kch * 1024); \
        bf16x8 c1 = *(const bf16x8*)(pstep + 8192 + kch * 1024); \
        ACC = __builtin_amdgcn_mfma_f32_32x32x16_bf16(c0, RB[0][kch], ACC, 0, 0, 0); \
        ACC = __builtin_amdgcn_mfma_f32_32x32x16_bf16(c1, RB[0][kch], ACC, 0, 0, 0); \
        ACC = __builtin_amdgcn_mfma_f32_32x32x16_bf16(c0, RB[1][kch], ACC, 0, 0, 0); \
    } \
    __builtin_amdgcn_s_setprio(0); }

// ---------------- fused: node_gemm (blocks 0-511) + kNN (blocks 512-1535) ----------------
__global__ __launch_bounds__(256, 3) void knn_node(const unsigned short* __restrict__ hs,
                                                   const float* __restrict__ sqg,
                                                   const unsigned short* __restrict__ Wt,
                                                   const float* __restrict__ ba,
                                                   float* __restrict__ P,
                                                   float* __restrict__ D,
                                                   float* __restrict__ cand_d)
{
    __shared__ ulong2 ldsraw[2176];   // 32KB dbuf + 2KB sq
    char* ldsc = (char*)ldsraw;
    const size_t plane = (size_t)NTOT * HD;
    const int t = threadIdx.x;
    const int wv = t >> 6, lane = t & 63;

    if (blockIdx.x < 512) {
        // ================= node GEMM =================
        const int lrow = lane & 15, kg = lane >> 4;
        const int nodebase = blockIdx.x * 64 + wv * 16;

        const unsigned short* arow = hs + (size_t)(nodebase + lrow) * HD + kg * 8;
        bf16x8 A0[4], A1[4];
#pragma unroll
        for (int kc = 0; kc < 4; ++kc) {
            A0[kc] = *(const bf16x8*)(arow + kc * 32);
            A1[kc] = *(const bf16x8*)(arow + plane + kc * 32);
        }

        char* ldsw = ldsc + wv * 1024;
        const unsigned short* wsrc = Wt + t * 8;
#pragma unroll
        for (int i = 0; i < 4; ++i)
            GLOAD_LDS16(wsrc + i * 2048, ldsw + i * 4096);
        __syncthreads();

        int cur = 0;
        for (int cs = 0; cs < 8; ++cs) {
            if (cs < 7) {
#pragma unroll
                for (int i = 0; i < 4; ++i)
                    GLOAD_LDS16(wsrc + (size_t)(cs + 1) * 12288 + i * 2048,
                                ldsc + (cur ^ 1) * 16384 + wv * 1024 + i * 4096);
            }
            const char* pb = ldsc + cur * 16384 + kg * 256 + lrow * 16;
            f32x4 acc0 = {0.f,0.f,0.f,0.f};
            f32x4 acc1 = {0.f,0.f,0.f,0.f};
#pragma unroll
            for (int kc = 0; kc < 4; ++kc) {
                const char* pk = pb + kc * 2048;
                bf16x8 b00 = *(const bf16x8*)(pk);
                bf16x8 b01 = *(const bf16x8*)(pk + 1024);
                bf16x8 b10 = *(const bf16x8*)(pk + 8192);
                bf16x8 b11 = *(const bf16x8*)(pk + 9216);
                THREEPASS(b00, b01, b10, b11)
            }
            int n0 = cs * 32 + lrow;
            if (cs < 4) {
#pragma unroll
                for (int r = 0; r < 4; ++r) {
                    size_t row = (size_t)(nodebase + kg * 4 + r) * HD;
                    P[row + n0]      = acc0[r];
                    P[row + n0 + 16] = acc1[r];
                }
            } else {
                float ba0 = ba[n0 - 128], ba1 = ba[n0 - 112];
#pragma unroll
                for (int r = 0; r < 4; ++r) {
                    size_t row = (size_t)(nodebase + kg * 4 + r) * HD;
                    D[row + n0 - 128] = acc0[r] + ba0;
                    D[row + n0 - 112] = acc1[r] + ba1;
                }
            }
            __syncthreads();
            cur ^= 1;
        }
        return;
    }

    // ================= kNN (4-way col split, sqj-in-acc, immediate select) =================
    float* sqs = (float*)(ldsc + 32768);
    const int b = blockIdx.x - 512;     // 1024 knn blocks
    const int slot = b >> 3;
    const int g  = (b & 7) | ((slot & 1) << 3);
    const int rb = (slot >> 1) & 15;
    const int cs = (slot >> 5) & 3;
    const int gbase = g * NPG;
    const int cbase = cs * 512;
    const int rl = lane & 31, kh = lane >> 5;
    const int myrow = rb * 128 + wv * 32 + rl;

    sqs[t]       = sqg[gbase + cbase + t];
    sqs[t + 256] = sqg[gbase + cbase + 256 + t];

    bf16x8 RB[2][8];
    {
        const unsigned short* rrow = hs + (size_t)(gbase + myrow) * HD + kh * 8;
#pragma unroll
        for (int p = 0; p < 2; ++p)
#pragma unroll
            for (int kch = 0; kch < 8; ++kch) {
                bf16x8 v = *(const bf16x8*)(rrow + (size_t)p * plane + kch * 16);
                unsigned* u = (unsigned*)&v;
#pragma unroll
                for (int w = 0; w < 4; ++w)
                    u[w] = (u[w] + 0x00800080u) ^ 0x80008000u;
                RB[p][kch] = v;
            }
    }

    const unsigned short* sb = hs + (size_t)(gbase + cbase + (t & 31)) * HD
                             + (t >> 6) * 16 + ((t >> 5) & 1) * 8;

#pragma unroll
    for (int i = 0; i < 4; ++i)
        GLOAD_LDS16(sb + (size_t)(i >> 1) * plane + (i & 1) * 64,
                    ldsc + wv * 1024 + i * 4096);
    __syncthreads();

    const float INF = __uint_as_float(0x7F800000u);
    float bd[8];
#pragma unroll
    for (int s = 0; s < 8; ++s) bd[s] = INF;

    f32x16 acc;
    int cur = 0;
    for (int s = 0; s < 16; ++s) {
        if (s < 15) {
            const unsigned short* sbn = sb + (size_t)(s + 1) * 32 * HD;
#pragma unroll
            for (int i = 0; i < 4; ++i)
                GLOAD_LDS16(sbn + (size_t)(i >> 1) * plane + (i & 1) * 64,
                            ldsc + (cur ^ 1) * 16384 + wv * 1024 + i * 4096);
        }
        KNN_MFMA_STEP(acc, s)
        SELECT(acc, s)
        __syncthreads();
        cur ^= 1;
    }

    // re-encode as GLOBAL keys: (bits & ~0x7FF) | j, vectorized 2x float4 store
    const size_t ob = (size_t)(gbase + myrow) * 64 + cs * 16 + kh * 8;
    f32x4 o0, o1;
#pragma unroll
    for (int sel = 0; sel < 8; ++sel) {
        unsigned u = __float_as_uint(bd[sel]);
        unsigned lid = u & 255u;
        unsigned j = (unsigned)(cbase + (int)(lid >> 4) * 32 + (int)((lid >> 2) & 3u) * 8
                              + kh * 4 + (int)(lid & 3u));
        float kv = __uint_as_float((u & 0xFFFFF800u) | j);
        if (sel < 4) o0[sel] = kv; else o1[sel - 4] = kv;
    }
    *(f32x4*)(cand_d + ob)     = o0;
    *(f32x4*)(cand_d + ob + 4) = o1;
}

// ---------------- fused edge kernel: 16 nodes/block, dual edge-groups/wave ----------------
template<bool FINAL>
__global__ __launch_bounds__(256) void edge_mlp(const float* __restrict__ P,
                                                const float* __restrict__ D,
                                                const float* __restrict__ cand_d,
                                                const unsigned short* __restrict__ Wbt,
                                                const float* __restrict__ bb,
                                                const float* __restrict__ w5,
                                                unsigned short* __restrict__ hsout,
                                                float* __restrict__ sqgout,
                                                float* __restrict__ out)
{
    __shared__ ulong2 ldsraw[2112];   // 32KB weights + 512B nbrs
    char* lds = (char*)ldsraw;
    int* nbrs = (int*)(lds + 32768);
    const size_t plane = (size_t)NTOT * HD;
    const int t = threadIdx.x, wv = t >> 6, lane = t & 63;
    const int lrow = lane & 15, kg = lane >> 4;
    const int node0 = blockIdx.x * 16;
    const int bn = node0 + wv * 4;     // wave's 4 nodes

    char* ldsw = lds + wv * 1024;
    const unsigned short* wsrc = Wbt + t * 8;
    if (!FINAL) {
#pragma unroll
        for (int i = 0; i < 4; ++i)
            GLOAD_LDS16(wsrc + i * 2048, ldsw + i * 4096);
    }

    // t<128: merge 16 rows' 8 sorted key-runs -> top-8 neighbor indices
    if (t < 128) {
        const int row = node0 + (t >> 3);
        const int run = t & 7;
        const int gb = (row >> 11) << 11;    // graph base
        const float* pd = cand_d + (size_t)row * 64 + run * 8;
        float d[8];
#pragma unroll
        for (int k = 0; k < 8; ++k) d[k] = pd[k];
        const float INF = __uint_as_float(0x7F800000u);
        float hd = d[0];
#pragma unroll
        for (int sel = 0; sel < 8; ++sel) {
            float md = hd;
#pragma unroll
            for (int m = 1; m < 8; m <<= 1)
                md = fminf(md, __shfl_xor(md, m, 8));
            if (run == sel)
                nbrs[(t >> 3) * 8 + sel] = gb + (int)(__float_as_uint(md) & 0x7FFu);
            bool win = (hd == md);     // keys unique -> exactly one winner
            if (win) {
                d[0]=d[1]; d[1]=d[2]; d[2]=d[3]; d[3]=d[4];
                d[4]=d[5]; d[5]=d[6]; d[6]=d[7]; d[7]=INF;
            }
            hd = d[0];
        }
    }
    __syncthreads();

    const int en = lrow >> 3;          // node within pair
    const int ee = lrow & 7;           // edge within node
    const int i0 = bn + en;            // group-a node
    const int i1 = bn + 2 + en;        // group-b node
    const int j0 = nbrs[(wv * 4 + en) * 8 + ee];
    const int j1 = nbrs[(wv * 4 + 2 + en) * 8 + ee];

    const float* dp0 = D + (size_t)i0 * HD + kg * 8;
    const float* pp0 = P + (size_t)j0 * HD + kg * 8;
    const float* dp1 = D + (size_t)i1 * HD + kg * 8;
    const float* pp1 = P + (size_t)j1 * HD + kg * 8;

    bf16x8 A0a[4], A1a[4], A0b[4], A1b[4];
    float sdot0 = 0.f, sdot1 = 0.f;
#pragma unroll
    for (int kc = 0; kc < 4; ++kc) {
#pragma unroll
        for (int gsel = 0; gsel < 2; ++gsel) {
            const float* dpx = gsel ? dp1 : dp0;
            const float* ppx = gsel ? pp1 : pp0;
            float4 d0 = *(const float4*)(dpx + kc * 32);
            float4 d1 = *(const float4*)(dpx + kc * 32 + 4);
            float4 p0 = *(const float4*)(ppx + kc * 32);
            float4 p1 = *(const float4*)(ppx + kc * 32 + 4);
            float v[8];
            v[0]=fmaxf(d0.x+p0.x,0.f); v[1]=fmaxf(d0.y+p0.y,0.f);
            v[2]=fmaxf(d0.z+p0.z,0.f); v[3]=fmaxf(d0.w+p0.w,0.f);
            v[4]=fmaxf(d1.x+p1.x,0.f); v[5]=fmaxf(d1.y+p1.y,0.f);
            v[6]=fmaxf(d1.z+p1.z,0.f); v[7]=fmaxf(d1.w+p1.w,0.f);
            if (FINAL) {
                float s = 0.f;
#pragma unroll
                for (int e = 0; e < 8; ++e)
                    s = fmaf(v[e], w5[kc * 32 + kg * 8 + e], s);
                if (gsel) sdot1 += s; else sdot0 += s;
            } else {
#pragma unroll
                for (int e = 0; e < 8; ++e) {
                    unsigned short b1 = bf16rn(v[e]); float r1 = v[e] - bf16tof(b1);
                    unsigned short b2 = bf16rn(r1);
                    if (gsel) { A0b[kc][e] = (short)b1; A1b[kc][e] = (short)b2; }
                    else      { A0a[kc][e] = (short)b1; A1a[kc][e] = (short)b2; }
                }
            }
        }
    }

    if (!FINAL) {
        const bool writer = (kg & 1) == 0;
        const int mn0 = bn + (kg >> 1);
        const int mn1 = bn + 2 + (kg >> 1);
        float sqacc0 = 0.f, sqacc1 = 0.f;

        int cur = 0;
        for (int cs = 0; cs < 4; ++cs) {
            if (cs < 3) {
#pragma unroll
                for (int i = 0; i < 4; ++i)
                    GLOAD_LDS16(wsrc + (size_t)(cs + 1) * 12288 + i * 2048,
                                lds + (cur ^ 1) * 16384 + wv * 1024 + i * 4096);
            }
            const char* pb = lds + cur * 16384 + kg * 256 + lrow * 16;
            f32x4 acc0a = {0.f,0.f,0.f,0.f}, acc1a = {0.f,0.f,0.f,0.f};
            f32x4 acc0b = {0.f,0.f,0.f,0.f}, acc1b = {0.f,0.f,0.f,0.f};
#pragma unroll
            for (int kc = 0; kc < 4; ++kc) {
                const char* pk = pb + kc * 2048;
                bf16x8 b00 = *(const bf16x8*)(pk);
                bf16x8 b01 = *(const bf16x8*)(pk + 1024);
                bf16x8 b10 = *(const bf16x8*)(pk + 8192);
                bf16x8 b11 = *(const bf16x8*)(pk + 9216);
                THREEPASS_G(A0a, A1a, b00, b01, b10, b11, acc0a, acc1a)
                THREEPASS_G(A0b, A1b, b00, b01, b10, b11, acc0b, acc1b)
            }
            float bb0 = bb[cs * 32 + lrow];
            float bb1 = bb[cs * 32 + 16 + lrow];
            // group a
            {
                float m0 = fmaxf(fmaxf(acc0a[0], acc0a[1]), fmaxf(acc0a[2], acc0a[3]));
                float m1 = fmaxf(fmaxf(acc1a[0], acc1a[1]), fmaxf(acc1a[2], acc1a[3]));
                m0 = fmaxf(m0 + bb0, 0.f);
                m1 = fmaxf(m1 + bb1, 0.f);
                m0 = fmaxf(m0, __shfl_xor(m0, 16));
                m1 = fmaxf(m1, __shfl_xor(m1, 16));
                if (writer) {
                    sqacc0 = fmaf(m0, m0, fmaf(m1, m1, sqacc0));
                    size_t base = (size_t)mn0 * HD + cs * 32 + lrow;
                    unsigned short c1 = bf16rn(m0); float r1 = m0 - bf16tof(c1);
                    unsigned short c2 = bf16rn(r1);
                    hsout[base]         = c1;
                    hsout[base + plane] = c2;
                    unsigned short e1 = bf16rn(m1); float s1 = m1 - bf16tof(e1);
                    unsigned short e2 = bf16rn(s1);
                    hsout[base + 16]         = e1;
                    hsout[base + 16 + plane] = e2;
                }
            }
            // group b
            {
                float m0 = fmaxf(fmaxf(acc0b[0], acc0b[1]), fmaxf(acc0b[2], acc0b[3]));
                float m1 = fmaxf(fmaxf(acc1b[0], acc1b[1]), fmaxf(acc1b[2], acc1b[3]));
                m0 = fmaxf(m0 + bb0, 0.f);
                m1 = fmaxf(m1 + bb1, 0.f);
                m0 = fmaxf(m0, __shfl_xor(m0, 16));
                m1 = fmaxf(m1, __shfl_xor(m1, 16));
                if (writer) {
                    sqacc1 = fmaf(m0, m0, fmaf(m1, m1, sqacc1));
                    size_t base = (size_t)mn1 * HD + cs * 32 + lrow;
                    unsigned short c1 = bf16rn(m0); float r1 = m0 - bf16tof(c1);
                    unsigned short c2 = bf16rn(r1);
                    hsout[base]         = c1;
                    hsout[base + plane] = c2;
                    unsigned short e1 = bf16rn(m1); float s1 = m1 - bf16tof(e1);
                    unsigned short e2 = bf16rn(s1);
                    hsout[base + 16]         = e1;
                    hsout[base + 16 + plane] = e2;
                }
            }
            __syncthreads();
            cur ^= 1;
        }
        if (writer) {
#pragma unroll
            for (int m = 1; m < 16; m <<= 1) {
                sqacc0 += __shfl_xor(sqacc0, m, 16);
                sqacc1 += __shfl_xor(sqacc1, m, 16);
            }
            if (lrow == 0) {
                sqgout[mn0] = sqacc0;
                sqgout[mn1] = sqacc1;
            }
        }
    } else {
        sdot0 += __shfl_xor(sdot0, 16);
        sdot0 += __shfl_xor(sdot0, 32);
        sdot1 += __shfl_xor(sdot1, 16);
        sdot1 += __shfl_xor(sdot1, 32);
        float s0 = fmaxf(sdot0 + bb[0], 0.f);
        float s1 = fmaxf(sdot1 + bb[0], 0.f);
#pragma unroll
        for (int m = 1; m < 8; m <<= 1) {
            s0 = fmaxf(s0, __shfl_xor(s0, m));
            s1 = fmaxf(s1, __shfl_xor(s1, m));
        }
        if (lane == 0) {
            out[bn]     = 1.f / (1.f + expf(-s0));
            out[bn + 2] = 1.f / (1.f + expf(-s1));
        }
        if (lane == 8) {
            out[bn + 1] = 1.f / (1.f + expf(-s0));
            out[bn + 3] = 1.f / (1.f + expf(-s1));
        }
    }
}

extern "C" void kernel_launch(void* const* d_in, const int* in_sizes, int n_in,
                              void* d_out, int out_size, void* d_ws, size_t ws_size,
                              hipStream_t stream) {
    const float* x     = (const float*)d_in[0];
    const float* W_enc = (const float*)d_in[3];
    const float* b_enc = (const float*)d_in[4];
    const float* W1a = (const float*)d_in[5];
    const float* b1a = (const float*)d_in[6];
    const float* W1b = (const float*)d_in[7];
    const float* b1b = (const float*)d_in[8];
    const float* W2a = (const float*)d_in[9];
    const float* b2a = (const float*)d_in[10];
    const float* W2b = (const float*)d_in[11];
    const float* b2b = (const float*)d_in[12];
    const float* W5a = (const float*)d_in[13];
    const float* b5a = (const float*)d_in[14];
    const float* W5b = (const float*)d_in[15];
    const float* b5b = (const float*)d_in[16];

    unsigned short* hs = (unsigned short*)d_ws;                  // 16 MB (2 planes)
    float* sqg  = (float*)(hs + (size_t)2*NTOT*HD);              // 128 KB
    float* cd   = sqg + NTOT;                                    // 8 MB (packed keys)
    float* Dbuf = cd + (size_t)NTOT*64;                          // 16 MB
    float* Pbuf = Dbuf + (size_t)NTOT*HD;                        // 16 MB
    unsigned short* Wt1  = (unsigned short*)(Pbuf + (size_t)NTOT*HD);
    unsigned short* Wt2  = Wt1 + 98304;
    unsigned short* Wt5  = Wt2 + 98304;
    unsigned short* Wbt1 = Wt5 + 98304;
    unsigned short* Wbt2 = Wbt1 + 49152;

    setup_all<<<8704, 256, 0, stream>>>(x, W_enc, b_enc, hs, sqg,
                                        W1a, W2a, W5a, W1b, W2b,
                                        Wt1, Wt2, Wt5, Wbt1, Wbt2);

    // layer 1 (hs updated in place by edge_mlp)
    knn_node<<<1536, 256, 0, stream>>>(hs, sqg, Wt1, b1a, Pbuf, Dbuf, cd);
    edge_mlp<false><<<NTOT/16, 256, 0, stream>>>(Pbuf, Dbuf, cd, Wbt1, b1b, nullptr, hs, sqg, nullptr);

    // layer 2
    knn_node<<<1536, 256, 0, stream>>>(hs, sqg, Wt2, b2a, Pbuf, Dbuf, cd);
    edge_mlp<false><<<NTOT/16, 256, 0, stream>>>(Pbuf, Dbuf, cd, Wbt2, b2b, nullptr, hs, sqg, nullptr);

    // layer 5 (final)
    knn_node<<<1536, 256, 0, stream>>>(hs, sqg, Wt5, b5a, Pbuf, Dbuf, cd);
    edge_mlp<true><<<NTOT/16, 256, 0, stream>>>(Pbuf, Dbuf, cd, nullptr, b5b, W5b, nullptr, nullptr, (float*)d_out);
}

// Round 20
// 303.179 us; speedup vs baseline: 1.0845x; 1.0286x over previous
//
#include <hip/hip_runtime.h>
#include <hip/hip_bf16.h>
#include <math.h>

#define BGR 16
#define NPG 2048
#define HD  128
#define KNN 8
#define NTOT (BGR*NPG)   // 32768

using bf16x8 = __attribute__((ext_vector_type(8))) short;
using f32x4  = __attribute__((ext_vector_type(4))) float;
using f32x16 = __attribute__((ext_vector_type(16))) float;

typedef __attribute__((address_space(3))) unsigned int lds_uint;
typedef const __attribute__((address_space(1))) unsigned int glob_uint;
#define GLOAD_LDS16(g, l) __builtin_amdgcn_global_load_lds((glob_uint*)(g), (lds_uint*)(l), 16, 0, 0)

__device__ inline unsigned short bf16rn(float f) {
    unsigned u = __float_as_uint(f);
    unsigned r = (u + 0x7FFFu + ((u >> 16) & 1u)) >> 16;
    return (unsigned short)r;
}
__device__ inline float bf16tof(unsigned short h) {
    return __uint_as_float(((unsigned)h) << 16);
}

// ---------------- fused setup: encoder+split+sqnorm AND all weight prep ----------------
__device__ inline void wcat_body(const float* __restrict__ Wa,
                                 unsigned short* __restrict__ Wt, int lb, int t)
{
    int gid = lb * 256 + t;        // 32768 = 128k x 256n
    int k = gid >> 8, n = gid & 255;
    float w;
    if (n < 128) w = Wa[(128 + k) * 128 + n];
    else { int nn = n - 128; w = Wa[k * 128 + nn] - Wa[(128 + k) * 128 + nn]; }
    unsigned short b1 = bf16rn(w);  float r1 = w - bf16tof(b1);
    unsigned short b2 = bf16rn(r1);
    int cs = n >> 5, h = (n >> 4) & 1, c = n & 15, kc = k >> 5, kg = (k >> 3) & 3, e = k & 7;
    size_t off = (size_t)cs * 12288 + kc * 1024 + h * 512 + kg * 128 + c * 8 + e;
    Wt[off] = b1; Wt[off + 4096] = b2;
}

__device__ inline void wb_body(const float* __restrict__ Wb,
                               unsigned short* __restrict__ Wt, int lb, int t)
{
    int gid = lb * 256 + t;        // 16384 = 128k x 128n
    int k = gid >> 7, n = gid & 127;
    float w = Wb[k * 128 + n];
    unsigned short b1 = bf16rn(w);  float r1 = w - bf16tof(b1);
    unsigned short b2 = bf16rn(r1);
    int cs = n >> 5, h = (n >> 4) & 1, c = n & 15, kc = k >> 5, kg = (k >> 3) & 3, e = k & 7;
    size_t off = (size_t)cs * 12288 + kc * 1024 + h * 512 + kg * 128 + c * 8 + e;
    Wt[off] = b1; Wt[off + 4096] = b2;
}

__global__ __launch_bounds__(256) void setup_all(const float* __restrict__ x,
                                                 const float* __restrict__ We,
                                                 const float* __restrict__ be,
                                                 unsigned short* __restrict__ hs,
                                                 float* __restrict__ sqg,
                                                 const float* __restrict__ W1a,
                                                 const float* __restrict__ W2a,
                                                 const float* __restrict__ W5a,
                                                 const float* __restrict__ W1b,
                                                 const float* __restrict__ W2b,
                                                 unsigned short* __restrict__ Wt1,
                                                 unsigned short* __restrict__ Wt2,
                                                 unsigned short* __restrict__ Wt5,
                                                 unsigned short* __restrict__ Wbt1,
                                                 unsigned short* __restrict__ Wbt2)
{
    const int bb = blockIdx.x, t = threadIdx.x;
    if (bb < 8192) {
        const size_t plane = (size_t)NTOT * HD;
        int node = (bb * 256 + t) >> 6;
        int lane = t & 63;
        float4 xv = *(const float4*)(x + (size_t)node * 4);
        float v0 = be[lane], v1 = be[lane + 64];
        const float* xf = (const float*)&xv;
#pragma unroll
        for (int f = 0; f < 4; ++f) {
            v0 = fmaf(xf[f], We[f * 128 + lane], v0);
            v1 = fmaf(xf[f], We[f * 128 + lane + 64], v1);
        }
        float s = fmaf(v0, v0, v1 * v1);
#pragma unroll
        for (int off = 32; off >= 1; off >>= 1)
            s += __shfl_xor(s, off);
        if (lane == 0) sqg[node] = s;
#pragma unroll
        for (int q = 0; q < 2; ++q) {
            float v = q ? v1 : v0;
            int   d = lane + q * 64;
            unsigned short b1 = bf16rn(v);  float r1 = v - bf16tof(b1);
            unsigned short b2 = bf16rn(r1);
            size_t base = (size_t)node * HD + d;
            hs[base]         = b1;
            hs[base + plane] = b2;
        }
    }
    else if (bb < 8320) wcat_body(W1a, Wt1, bb - 8192, t);
    else if (bb < 8448) wcat_body(W2a, Wt2, bb - 8320, t);
    else if (bb < 8576) wcat_body(W5a, Wt5, bb - 8448, t);
    else if (bb < 8640) wb_body(W1b, Wbt1, bb - 8576, t);
    else                wb_body(W2b, Wbt2, bb - 8640, t);
}

// 3-pass: A0B0 + A1B0 + A0B1 (drop O(2^-16) A1B1 cross term)
#define THREEPASS(B00,B01,B10,B11) \
    acc0 = __builtin_amdgcn_mfma_f32_16x16x32_bf16(A0[kc], B00, acc0, 0, 0, 0); \
    acc1 = __builtin_amdgcn_mfma_f32_16x16x32_bf16(A0[kc], B01, acc1, 0, 0, 0); \
    acc0 = __builtin_amdgcn_mfma_f32_16x16x32_bf16(A1[kc], B00, acc0, 0, 0, 0); \
    acc1 = __builtin_amdgcn_mfma_f32_16x16x32_bf16(A1[kc], B01, acc1, 0, 0, 0); \
    acc0 = __builtin_amdgcn_mfma_f32_16x16x32_bf16(A0[kc], B10, acc0, 0, 0, 0); \
    acc1 = __builtin_amdgcn_mfma_f32_16x16x32_bf16(A0[kc], B11, acc1, 0, 0, 0);

// parameterized 3-pass for dual edge-groups
#define THREEPASS_G(AA0,AA1,B00,B01,B10,B11,C0,C1) \
    C0 = __builtin_amdgcn_mfma_f32_16x16x32_bf16(AA0[kc], B00, C0, 0, 0, 0); \
    C1 = __builtin_amdgcn_mfma_f32_16x16x32_bf16(AA0[kc], B01, C1, 0, 0, 0); \
    C0 = __builtin_amdgcn_mfma_f32_16x16x32_bf16(AA1[kc], B00, C0, 0, 0, 0); \
    C1 = __builtin_amdgcn_mfma_f32_16x16x32_bf16(AA1[kc], B01, C1, 0, 0, 0); \
    C0 = __builtin_amdgcn_mfma_f32_16x16x32_bf16(AA0[kc], B10, C0, 0, 0, 0); \
    C1 = __builtin_amdgcn_mfma_f32_16x16x32_bf16(AA0[kc], B11, C1, 0, 0, 0);

// selection: accA holds sqj + partial(-2dot), accB the rest; key = pack(accA+accB)
#define SELECT(PA, PB, PS) { \
    const unsigned lidbase = (unsigned)((PS) << 4); \
    _Pragma("unroll") \
    for (int i = 0; i < 16; ++i) { \
        float dsum = (PA)[i] + (PB)[i]; \
        unsigned ku = (__float_as_uint(dsum) & 0xFFFFFF00u) \
                    | (lidbase + (unsigned)i); \
        float kk = __uint_as_float(ku); \
        bd[7] = __builtin_amdgcn_fmed3f(bd[6], kk, bd[7]); \
        bd[6] = __builtin_amdgcn_fmed3f(bd[5], kk, bd[6]); \
        bd[5] = __builtin_amdgcn_fmed3f(bd[4], kk, bd[5]); \
        bd[4] = __builtin_amdgcn_fmed3f(bd[3], kk, bd[4]); \
        bd[3] = __builtin_amdgcn_fmed3f(bd[2], kk, bd[3]); \
        bd[2] = __builtin_amdgcn_fmed3f(bd[1], kk, bd[2]); \
        bd[1] = __builtin_amdgcn_fmed3f(bd[0], kk, bd[1]); \
        bd[0] = fminf(bd[0], kk); \
    } }

// MFMA step: two independent 12-MFMA chains (A init = sqj, B init = 0)
#define KNN_MFMA_STEP(ACCA, ACCB, S) { \
    const float* qq = sqs + (S) * 32 + kh * 4; \
    f32x4 q0 = *(const f32x4*)(qq); \
    f32x4 q1 = *(const f32x4*)(qq + 8); \
    f32x4 q2 = *(const f32x4*)(qq + 16); \
    f32x4 q3 = *(const f32x4*)(qq + 24); \
    ACCA[0]=q0[0]; ACCA[1]=q0[1]; ACCA[2]=q0[2]; ACCA[3]=q0[3]; \
    ACCA[4]=q1[0]; ACCA[5]=q1[1]; ACCA[6]=q1[2]; ACCA[7]=q1[3]; \
    ACCA[8]=q2[0]; ACCA[9]=q2[1]; ACCA[10]=q2[2]; ACCA[11]=q2[3]; \
    ACCA[12]=q3[0]; ACCA[13]=q3[1]; ACCA[14]=q3[2]; ACCA[15]=q3[3]; \
    ACCB = (f32x16){0.f,0.f,0.f,0.f,0.f,0.f,0.f,0.f,0.f,0.f,0.f,0.f,0.f,0.f,0.f,0.f}; \
    const char* pstep = ldsc + cur * 16384 + lane * 16; \
    __builtin_amdgcn_s_setprio(1); \
    _Pragma("unroll") \
    for (int kch = 0; kch < 8; ++kch) { \
        bf16x8 c0 = *(const bf16x8*)(pstep + kch * 1024); \
        bf16x8 c1 = *(const bf16x8*)(pstep + 8192 + kch * 1024); \
        ACCA = __builtin_amdgcn_mfma_f32_32x32x16_bf16(c0, RB[0][kch], ACCA, 0, 0, 0); \
        ACCB = __builtin_amdgcn_mfma_f32_32x32x16_bf16(c1, RB[0][kch], ACCB, 0, 0, 0); \
        if (kch & 1) ACCA = __builtin_amdgcn_mfma_f32_32x32x16_bf16(c0, RB[1][kch], ACCA, 0, 0, 0); \
        else         ACCB = __builtin_amdgcn_mfma_f32_32x32x16_bf16(c0, RB[1][kch], ACCB, 0, 0, 0); \
    } \
    __builtin_amdgcn_s_setprio(0); }

// ---------------- fused: node_gemm (blocks 0-511) + kNN (blocks 512-1535) ----------------
__global__ __launch_bounds__(256, 3) void knn_node(const unsigned short* __restrict__ hs,
                                                   const float* __restrict__ sqg,
                                                   const unsigned short* __restrict__ Wt,
                                                   const float* __restrict__ ba,
                                                   float* __restrict__ P,
                                                   float* __restrict__ D,
                                                   float* __restrict__ cand_d)
{
    __shared__ ulong2 ldsraw[2176];   // 32KB dbuf + 2KB sq
    char* ldsc = (char*)ldsraw;
    const size_t plane = (size_t)NTOT * HD;
    const int t = threadIdx.x;
    const int wv = t >> 6, lane = t & 63;

    if (blockIdx.x < 512) {
        // ================= node GEMM =================
        const int lrow = lane & 15, kg = lane >> 4;
        const int nodebase = blockIdx.x * 64 + wv * 16;

        const unsigned short* arow = hs + (size_t)(nodebase + lrow) * HD + kg * 8;
        bf16x8 A0[4], A1[4];
#pragma unroll
        for (int kc = 0; kc < 4; ++kc) {
            A0[kc] = *(const bf16x8*)(arow + kc * 32);
            A1[kc] = *(const bf16x8*)(arow + plane + kc * 32);
        }

        char* ldsw = ldsc + wv * 1024;
        const unsigned short* wsrc = Wt + t * 8;
#pragma unroll
        for (int i = 0; i < 4; ++i)
            GLOAD_LDS16(wsrc + i * 2048, ldsw + i * 4096);
        __syncthreads();

        int cur = 0;
        for (int cs = 0; cs < 8; ++cs) {
            if (cs < 7) {
#pragma unroll
                for (int i = 0; i < 4; ++i)
                    GLOAD_LDS16(wsrc + (size_t)(cs + 1) * 12288 + i * 2048,
                                ldsc + (cur ^ 1) * 16384 + wv * 1024 + i * 4096);
            }
            const char* pb = ldsc + cur * 16384 + kg * 256 + lrow * 16;
            f32x4 acc0 = {0.f,0.f,0.f,0.f};
            f32x4 acc1 = {0.f,0.f,0.f,0.f};
#pragma unroll
            for (int kc = 0; kc < 4; ++kc) {
                const char* pk = pb + kc * 2048;
                bf16x8 b00 = *(const bf16x8*)(pk);
                bf16x8 b01 = *(const bf16x8*)(pk + 1024);
                bf16x8 b10 = *(const bf16x8*)(pk + 8192);
                bf16x8 b11 = *(const bf16x8*)(pk + 9216);
                THREEPASS(b00, b01, b10, b11)
            }
            int n0 = cs * 32 + lrow;
            if (cs < 4) {
#pragma unroll
                for (int r = 0; r < 4; ++r) {
                    size_t row = (size_t)(nodebase + kg * 4 + r) * HD;
                    P[row + n0]      = acc0[r];
                    P[row + n0 + 16] = acc1[r];
                }
            } else {
                float ba0 = ba[n0 - 128], ba1 = ba[n0 - 112];
#pragma unroll
                for (int r = 0; r < 4; ++r) {
                    size_t row = (size_t)(nodebase + kg * 4 + r) * HD;
                    D[row + n0 - 128] = acc0[r] + ba0;
                    D[row + n0 - 112] = acc1[r] + ba1;
                }
            }
            __syncthreads();
            cur ^= 1;
        }
        return;
    }

    // ================= kNN (4-way col split, dual chains, sqj-in-accA) =================
    float* sqs = (float*)(ldsc + 32768);
    const int b = blockIdx.x - 512;     // 1024 knn blocks
    const int slot = b >> 3;
    const int g  = (b & 7) | ((slot & 1) << 3);
    const int rb = (slot >> 1) & 15;
    const int cs = (slot >> 5) & 3;
    const int gbase = g * NPG;
    const int cbase = cs * 512;
    const int rl = lane & 31, kh = lane >> 5;
    const int myrow = rb * 128 + wv * 32 + rl;

    sqs[t]       = sqg[gbase + cbase + t];
    sqs[t + 256] = sqg[gbase + cbase + 256 + t];

    bf16x8 RB[2][8];
    {
        const unsigned short* rrow = hs + (size_t)(gbase + myrow) * HD + kh * 8;
#pragma unroll
        for (int p = 0; p < 2; ++p)
#pragma unroll
            for (int kch = 0; kch < 8; ++kch) {
                bf16x8 v = *(const bf16x8*)(rrow + (size_t)p * plane + kch * 16);
                unsigned* u = (unsigned*)&v;
#pragma unroll
                for (int w = 0; w < 4; ++w)
                    u[w] = (u[w] + 0x00800080u) ^ 0x80008000u;
                RB[p][kch] = v;
            }
    }

    const unsigned short* sb = hs + (size_t)(gbase + cbase + (t & 31)) * HD
                             + (t >> 6) * 16 + ((t >> 5) & 1) * 8;

#pragma unroll
    for (int i = 0; i < 4; ++i)
        GLOAD_LDS16(sb + (size_t)(i >> 1) * plane + (i & 1) * 64,
                    ldsc + wv * 1024 + i * 4096);
    __syncthreads();

    const float INF = __uint_as_float(0x7F800000u);
    float bd[8];
#pragma unroll
    for (int s = 0; s < 8; ++s) bd[s] = INF;

    f32x16 accA, accB;
    int cur = 0;
    for (int s = 0; s < 16; ++s) {
        if (s < 15) {
            const unsigned short* sbn = sb + (size_t)(s + 1) * 32 * HD;
#pragma unroll
            for (int i = 0; i < 4; ++i)
                GLOAD_LDS16(sbn + (size_t)(i >> 1) * plane + (i & 1) * 64,
                            ldsc + (cur ^ 1) * 16384 + wv * 1024 + i * 4096);
        }
        KNN_MFMA_STEP(accA, accB, s)
        SELECT(accA, accB, s)
        __syncthreads();
        cur ^= 1;
    }

    // re-encode as GLOBAL keys: (bits & ~0x7FF) | j, vectorized 2x float4 store
    const size_t ob = (size_t)(gbase + myrow) * 64 + cs * 16 + kh * 8;
    f32x4 o0, o1;
#pragma unroll
    for (int sel = 0; sel < 8; ++sel) {
        unsigned u = __float_as_uint(bd[sel]);
        unsigned lid = u & 255u;
        unsigned j = (unsigned)(cbase + (int)(lid >> 4) * 32 + (int)((lid >> 2) & 3u) * 8
                              + kh * 4 + (int)(lid & 3u));
        float kv = __uint_as_float((u & 0xFFFFF800u) | j);
        if (sel < 4) o0[sel] = kv; else o1[sel - 4] = kv;
    }
    *(f32x4*)(cand_d + ob)     = o0;
    *(f32x4*)(cand_d + ob + 4) = o1;
}

// ---------------- fused edge kernel: 16 nodes/block, dual edge-groups/wave ----------------
template<bool FINAL>
__global__ __launch_bounds__(256) void edge_mlp(const float* __restrict__ P,
                                                const float* __restrict__ D,
                                                const float* __restrict__ cand_d,
                                                const unsigned short* __restrict__ Wbt,
                                                const float* __restrict__ bb,
                                                const float* __restrict__ w5,
                                                unsigned short* __restrict__ hsout,
                                                float* __restrict__ sqgout,
                                                float* __restrict__ out)
{
    __shared__ ulong2 ldsraw[2112];   // 32KB weights + 512B nbrs
    char* lds = (char*)ldsraw;
    int* nbrs = (int*)(lds + 32768);
    const size_t plane = (size_t)NTOT * HD;
    const int t = threadIdx.x, wv = t >> 6, lane = t & 63;
    const int lrow = lane & 15, kg = lane >> 4;
    const int node0 = blockIdx.x * 16;
    const int bn = node0 + wv * 4;     // wave's 4 nodes

    char* ldsw = lds + wv * 1024;
    const unsigned short* wsrc = Wbt + t * 8;
    if (!FINAL) {
#pragma unroll
        for (int i = 0; i < 4; ++i)
            GLOAD_LDS16(wsrc + i * 2048, ldsw + i * 4096);
    }

    // t<128: merge 16 rows' 8 sorted key-runs -> top-8 neighbor indices
    if (t < 128) {
        const int row = node0 + (t >> 3);
        const int run = t & 7;
        const int gb = (row >> 11) << 11;    // graph base
        const float* pd = cand_d + (size_t)row * 64 + run * 8;
        float d[8];
#pragma unroll
        for (int k = 0; k < 8; ++k) d[k] = pd[k];
        const float INF = __uint_as_float(0x7F800000u);
        float hd = d[0];
#pragma unroll
        for (int sel = 0; sel < 8; ++sel) {
            float md = hd;
#pragma unroll
            for (int m = 1; m < 8; m <<= 1)
                md = fminf(md, __shfl_xor(md, m, 8));
            if (run == sel)
                nbrs[(t >> 3) * 8 + sel] = gb + (int)(__float_as_uint(md) & 0x7FFu);
            bool win = (hd == md);     // keys unique -> exactly one winner
            if (win) {
                d[0]=d[1]; d[1]=d[2]; d[2]=d[3]; d[3]=d[4];
                d[4]=d[5]; d[5]=d[6]; d[6]=d[7]; d[7]=INF;
            }
            hd = d[0];
        }
    }
    __syncthreads();

    const int en = lrow >> 3;          // node within pair
    const int ee = lrow & 7;           // edge within node
    const int i0 = bn + en;            // group-a node
    const int i1 = bn + 2 + en;        // group-b node
    const int j0 = nbrs[(wv * 4 + en) * 8 + ee];
    const int j1 = nbrs[(wv * 4 + 2 + en) * 8 + ee];

    const float* dp0 = D + (size_t)i0 * HD + kg * 8;
    const float* pp0 = P + (size_t)j0 * HD + kg * 8;
    const float* dp1 = D + (size_t)i1 * HD + kg * 8;
    const float* pp1 = P + (size_t)j1 * HD + kg * 8;

    bf16x8 A0a[4], A1a[4], A0b[4], A1b[4];
    float sdot0 = 0.f, sdot1 = 0.f;
#pragma unroll
    for (int kc = 0; kc < 4; ++kc) {
#pragma unroll
        for (int gsel = 0; gsel < 2; ++gsel) {
            const float* dpx = gsel ? dp1 : dp0;
            const float* ppx = gsel ? pp1 : pp0;
            float4 d0 = *(const float4*)(dpx + kc * 32);
            float4 d1 = *(const float4*)(dpx + kc * 32 + 4);
            float4 p0 = *(const float4*)(ppx + kc * 32);
            float4 p1 = *(const float4*)(ppx + kc * 32 + 4);
            float v[8];
            v[0]=fmaxf(d0.x+p0.x,0.f); v[1]=fmaxf(d0.y+p0.y,0.f);
            v[2]=fmaxf(d0.z+p0.z,0.f); v[3]=fmaxf(d0.w+p0.w,0.f);
            v[4]=fmaxf(d1.x+p1.x,0.f); v[5]=fmaxf(d1.y+p1.y,0.f);
            v[6]=fmaxf(d1.z+p1.z,0.f); v[7]=fmaxf(d1.w+p1.w,0.f);
            if (FINAL) {
                float s = 0.f;
#pragma unroll
                for (int e = 0; e < 8; ++e)
                    s = fmaf(v[e], w5[kc * 32 + kg * 8 + e], s);
                if (gsel) sdot1 += s; else sdot0 += s;
            } else {
#pragma unroll
                for (int e = 0; e < 8; ++e) {
                    unsigned short b1 = bf16rn(v[e]); float r1 = v[e] - bf16tof(b1);
                    unsigned short b2 = bf16rn(r1);
                    if (gsel) { A0b[kc][e] = (short)b1; A1b[kc][e] = (short)b2; }
                    else      { A0a[kc][e] = (short)b1; A1a[kc][e] = (short)b2; }
                }
            }
        }
    }

    if (!FINAL) {
        const bool writer = (kg & 1) == 0;
        const int mn0 = bn + (kg >> 1);
        const int mn1 = bn + 2 + (kg >> 1);
        float sqacc0 = 0.f, sqacc1 = 0.f;

        int cur = 0;
        for (int cs = 0; cs < 4; ++cs) {
            if (cs < 3) {
#pragma unroll
                for (int i = 0; i < 4; ++i)
                    GLOAD_LDS16(wsrc + (size_t)(cs + 1) * 12288 + i * 2048,
                                lds + (cur ^ 1) * 16384 + wv * 1024 + i * 4096);
            }
            const char* pb = lds + cur * 16384 + kg * 256 + lrow * 16;
            f32x4 acc0a = {0.f,0.f,0.f,0.f}, acc1a = {0.f,0.f,0.f,0.f};
            f32x4 acc0b = {0.f,0.f,0.f,0.f}, acc1b = {0.f,0.f,0.f,0.f};
#pragma unroll
            for (int kc = 0; kc < 4; ++kc) {
                const char* pk = pb + kc * 2048;
                bf16x8 b00 = *(const bf16x8*)(pk);
                bf16x8 b01 = *(const bf16x8*)(pk + 1024);
                bf16x8 b10 = *(const bf16x8*)(pk + 8192);
                bf16x8 b11 = *(const bf16x8*)(pk + 9216);
                THREEPASS_G(A0a, A1a, b00, b01, b10, b11, acc0a, acc1a)
                THREEPASS_G(A0b, A1b, b00, b01, b10, b11, acc0b, acc1b)
            }
            float bb0 = bb[cs * 32 + lrow];
            float bb1 = bb[cs * 32 + 16 + lrow];
            // group a
            {
                float m0 = fmaxf(fmaxf(acc0a[0], acc0a[1]), fmaxf(acc0a[2], acc0a[3]));
                float m1 = fmaxf(fmaxf(acc1a[0], acc1a[1]), fmaxf(acc1a[2], acc1a[3]));
                m0 = fmaxf(m0 + bb0, 0.f);
                m1 = fmaxf(m1 + bb1, 0.f);
                m0 = fmaxf(m0, __shfl_xor(m0, 16));
                m1 = fmaxf(m1, __shfl_xor(m1, 16));
                if (writer) {
                    sqacc0 = fmaf(m0, m0, fmaf(m1, m1, sqacc0));
                    size_t base = (size_t)mn0 * HD + cs * 32 + lrow;
                    unsigned short c1 = bf16rn(m0); float r1 = m0 - bf16tof(c1);
                    unsigned short c2 = bf16rn(r1);
                    hsout[base]         = c1;
                    hsout[base + plane] = c2;
                    unsigned short e1 = bf16rn(m1); float s1 = m1 - bf16tof(e1);
                    unsigned short e2 = bf16rn(s1);
                    hsout[base + 16]         = e1;
                    hsout[base + 16 + plane] = e2;
                }
            }
            // group b
            {
                float m0 = fmaxf(fmaxf(acc0b[0], acc0b[1]), fmaxf(acc0b[2], acc0b[3]));
                float m1 = fmaxf(fmaxf(acc1b[0], acc1b[1]), fmaxf(acc1b[2], acc1b[3]));
                m0 = fmaxf(m0 + bb0, 0.f);
                m1 = fmaxf(m1 + bb1, 0.f);
                m0 = fmaxf(m0, __shfl_xor(m0, 16));
                m1 = fmaxf(m1, __shfl_xor(m1, 16));
                if (writer) {
                    sqacc1 = fmaf(m0, m0, fmaf(m1, m1, sqacc1));
                    size_t base = (size_t)mn1 * HD + cs * 32 + lrow;
                    unsigned short c1 = bf16rn(m0); float r1 = m0 - bf16tof(c1);
                    unsigned short c2 = bf16rn(r1);
                    hsout[base]         = c1;
                    hsout[base + plane] = c2;
                    unsigned short e1 = bf16rn(m1); float s1 = m1 - bf16tof(e1);
                    unsigned short e2 = bf16rn(s1);
                    hsout[base + 16]         = e1;
                    hsout[base + 16 + plane] = e2;
                }
            }
            __syncthreads();
            cur ^= 1;
        }
        if (writer) {
#pragma unroll
            for (int m = 1; m < 16; m <<= 1) {
                sqacc0 += __shfl_xor(sqacc0, m, 16);
                sqacc1 += __shfl_xor(sqacc1, m, 16);
            }
            if (lrow == 0) {
                sqgout[mn0] = sqacc0;
                sqgout[mn1] = sqacc1;
            }
        }
    } else {
        sdot0 += __shfl_xor(sdot0, 16);
        sdot0 += __shfl_xor(sdot0, 32);
        sdot1 += __shfl_xor(sdot1, 16);
        sdot1 += __shfl_xor(sdot1, 32);
        float s0 = fmaxf(sdot0 + bb[0], 0.f);
        float s1 = fmaxf(sdot1 + bb[0], 0.f);
#pragma unroll
        for (int m = 1; m < 8; m <<= 1) {
            s0 = fmaxf(s0, __shfl_xor(s0, m));
            s1 = fmaxf(s1, __shfl_xor(s1, m));
        }
        if (lane == 0) {
            out[bn]     = 1.f / (1.f + expf(-s0));
            out[bn + 2] = 1.f / (1.f + expf(-s1));
        }
        if (lane == 8) {
            out[bn + 1] = 1.f / (1.f + expf(-s0));
            out[bn + 3] = 1.f / (1.f + expf(-s1));
        }
    }
}

extern "C" void kernel_launch(void* const* d_in, const int* in_sizes, int n_in,
                              void* d_out, int out_size, void* d_ws, size_t ws_size,
                              hipStream_t stream) {
    const float* x     = (const float*)d_in[0];
    const float* W_enc = (const float*)d_in[3];
    const float* b_enc = (const float*)d_in[4];
    const float* W1a = (const float*)d_in[5];
    const float* b1a = (const float*)d_in[6];
    const float* W1b = (const float*)d_in[7];
    const float* b1b = (const float*)d_in[8];
    const float* W2a = (const float*)d_in[9];
    const float* b2a = (const float*)d_in[10];
    const float* W2b = (const float*)d_in[11];
    const float* b2b = (const float*)d_in[12];
    const float* W5a = (const float*)d_in[13];
    const float* b5a = (const float*)d_in[14];
    const float* W5b = (const float*)d_in[15];
    const float* b5b = (const float*)d_in[16];

    unsigned short* hs = (unsigned short*)d_ws;                  // 16 MB (2 planes)
    float* sqg  = (float*)(hs + (size_t)2*NTOT*HD);              // 128 KB
    float* cd   = sqg + NTOT;                                    // 8 MB (packed keys)
    float* Dbuf = cd + (size_t)NTOT*64;                          // 16 MB
    float* Pbuf = Dbuf + (size_t)NTOT*HD;                        // 16 MB
    unsigned short* Wt1  = (unsigned short*)(Pbuf + (size_t)NTOT*HD);
    unsigned short* Wt2  = Wt1 + 98304;
    unsigned short* Wt5  = Wt2 + 98304;
    unsigned short* Wbt1 = Wt5 + 98304;
    unsigned short* Wbt2 = Wbt1 + 49152;

    setup_all<<<8704, 256, 0, stream>>>(x, W_enc, b_enc, hs, sqg,
                                        W1a, W2a, W5a, W1b, W2b,
                                        Wt1, Wt2, Wt5, Wbt1, Wbt2);

    // layer 1 (hs updated in place by edge_mlp)
    knn_node<<<1536, 256, 0, stream>>>(hs, sqg, Wt1, b1a, Pbuf, Dbuf, cd);
    edge_mlp<false><<<NTOT/16, 256, 0, stream>>>(Pbuf, Dbuf, cd, Wbt1, b1b, nullptr, hs, sqg, nullptr);

    // layer 2
    knn_node<<<1536, 256, 0, stream>>>(hs, sqg, Wt2, b2a, Pbuf, Dbuf, cd);
    edge_mlp<false><<<NTOT/16, 256, 0, stream>>>(Pbuf, Dbuf, cd, Wbt2, b2b, nullptr, hs, sqg, nullptr);

    // layer 5 (final)
    knn_node<<<1536, 256, 0, stream>>>(hs, sqg, Wt5, b5a, Pbuf, Dbuf, cd);
    edge_mlp<true><<<NTOT/16, 256, 0, stream>>>(Pbuf, Dbuf, cd, nullptr, b5b, W5b, nullptr, nullptr, (float*)d_out);
}